// Round 14
// baseline (260.989 us; speedup 1.0000x reference)
//
#include <hip/hip_runtime.h>
#include <hip/hip_fp16.h>
#include <math.h>

#define SELU_LAMBDA 1.0507009873554805f
#define SELU_ALPHA  1.6732632423543772f

#define BSHIFT 9
#define BNODES 512          // nodes per bucket
#define CAP    10240        // bucket capacity (mean 8192, +22 sigma)
#define CHUNK  4096         // edges per k_bin block
#define NSLOT  64           // stats atomic spreading slots

typedef _Float16 half8 __attribute__((ext_vector_type(8)));
typedef float f32x4 __attribute__((ext_vector_type(4)));

// fp16 helpers
__device__ __forceinline__ unsigned int f2h2(float a, float b) {
  __half2 h = __floats2half2_rn(a, b);
  return *(unsigned int*)&h;
}
__device__ __forceinline__ float2 h22f2(unsigned int u) {
  __half2 h = *(__half2*)&u;
  return __half22float2(h);
}
__device__ __forceinline__ unsigned int hadd2(unsigned int a, unsigned int b) {
  __half2 x = *(__half2*)&a, y = *(__half2*)&b;
  __half2 r = __hadd2(x, y);
  return *(unsigned int*)&r;
}

// ---------------------------------------------------------------- setup: zero cursor/stats/pads + W1 MFMA-fragment prep
__global__ __launch_bounds__(256) void k_setup(int* __restrict__ cursor,
    float* __restrict__ stats, unsigned short* __restrict__ h1,
    unsigned short* __restrict__ h2, unsigned short* __restrict__ yb,
    const float* __restrict__ W1, unsigned short* __restrict__ Wfrag, int n) {
  int i = blockIdx.x * 256 + threadIdx.x;
  if (i < 256) cursor[i] = 0;
  if (i < NSLOT * 128) stats[i] = 0.f;
  size_t H1S = (size_t)(n + 1) * 32;
  if (i < 64) {   // zero-pad row N in both halves of h1, h2
    size_t off = (size_t)(i >> 5) * H1S + (size_t)n * 32 + (i & 31);
    h1[off] = 0;
    h2[off] = 0;
  }
  if (i < 16) yb[(size_t)n * 16 + i] = 0;
  if (i < 1024) {  // Wfrag[(ntile*4+kb)*64+lane][8]
    int lane = i & 63;
    int kb = (i >> 6) & 3;
    int ntile = i >> 8;
    int k0 = kb * 32 + (lane >> 4) * 8;
    int col = ntile * 16 + (lane & 15);
    unsigned short tmp[8];
#pragma unroll
    for (int j = 0; j < 8; ++j) {
      __half h = __float2half_rn(W1[(size_t)(k0 + j) * 64 + col]);
      tmp[j] = *(unsigned short*)&h;
    }
    *(uint4*)&Wfrag[(size_t)i * 8] = *(uint4*)tmp;
  }
}

// ---------------------------------------------------------------- phase 1: bin edges by dst bucket
__global__ __launch_bounds__(256) void k_bin(const int* __restrict__ src,
    const int* __restrict__ dst, int* __restrict__ cursor,
    int* __restrict__ binned, int e) {
  __shared__ int hist[256];
  __shared__ int gb[256];
  const int tid = threadIdx.x;
  hist[tid] = 0;
  __syncthreads();
  const int base = blockIdx.x * CHUNK;
  int bk[16], rk[16], pk[16];
#pragma unroll
  for (int k = 0; k < 16; ++k) {
    int i = base + k * 256 + tid;
    if (i < e) {
      int d = dst[i];
      int s = src[i];
      int b = d >> BSHIFT;
      bk[k] = b;
      pk[k] = s | ((d & (BNODES - 1)) << 17);
      rk[k] = atomicAdd(&hist[b], 1);
    } else {
      bk[k] = -1;
    }
  }
  __syncthreads();
  int h = hist[tid];
  if (h > 0) gb[tid] = atomicAdd(&cursor[tid], h);
  __syncthreads();
#pragma unroll
  for (int k = 0; k < 16; ++k) {
    if (bk[k] >= 0) binned[bk[k] * CAP + gb[bk[k]] + rk[k]] = pk[k];
  }
}

// ---------------------------------------------------------------- phase 2: per-bucket CSR build
__global__ __launch_bounds__(256) void k_build(const int* __restrict__ binned,
    const int* __restrict__ cursor, int* __restrict__ offs,
    int* __restrict__ csr, int n, int nb, int etot) {
  __shared__ int sc[2][256];
  __shared__ int deg[BNODES];
  __shared__ int pre[BNODES];
  __shared__ int wsum[4];
  __shared__ int stage[CAP];
  __shared__ int s_cbase;
  const int b = blockIdx.x;
  const int tid = threadIdx.x;

  int v0 = (tid < nb) ? cursor[tid] : 0;
  sc[0][tid] = v0;
  __syncthreads();
  int cur = 0;
  for (int d = 1; d < 256; d <<= 1) {
    int t = sc[cur][tid];
    if (tid >= d) t += sc[cur][tid - d];
    sc[cur ^ 1][tid] = t;
    cur ^= 1;
    __syncthreads();
  }
  if (tid == 0) {
    s_cbase = (b == 0) ? 0 : sc[cur][b - 1];
    if (b == 0) offs[n] = etot;
  }
  deg[tid] = 0;
  deg[tid + 256] = 0;
  __syncthreads();
  const int cbase = s_cbase;
  const int cnt = sc[cur][b] - cbase;

  const int nodeBase = b << BSHIFT;
  const int* gsrc = binned + b * CAP;

  for (int i = tid; i < cnt; i += 256) atomicAdd(&deg[gsrc[i] >> 17], 1);
  __syncthreads();

  const int lane = tid & 63, w = tid >> 6;
  int a0 = deg[2 * tid], a1 = deg[2 * tid + 1];
  int ps = a0 + a1;
  int s = ps;
#pragma unroll
  for (int d = 1; d < 64; d <<= 1) {
    int t = __shfl_up(s, d, 64);
    if (lane >= d) s += t;
  }
  if (lane == 63) wsum[w] = s;
  __syncthreads();
  if (tid == 0) {
    int acc = 0;
#pragma unroll
    for (int j = 0; j < 4; ++j) { int t = wsum[j]; wsum[j] = acc; acc += t; }
  }
  __syncthreads();
  int ex = wsum[w] + s - ps;
  pre[2 * tid] = ex;
  pre[2 * tid + 1] = ex + a0;
  deg[tid] = 0;
  deg[tid + 256] = 0;
  __syncthreads();

  const int nNodes = min(BNODES, n - nodeBase);
  for (int i = tid; i < nNodes; i += 256) offs[nodeBase + i] = cbase + pre[i];

  for (int i = tid; i < cnt; i += 256) {
    int v = gsrc[i];
    int dl = v >> 17;
    int p = pre[dl] + atomicAdd(&deg[dl], 1);
    stage[p] = v & 0x1FFFF;
  }
  __syncthreads();
  for (int i = tid; i < cnt; i += 256) csr[cbase + i] = stage[i];
}

// ---------------------------------------------------------------- GEMM1 via MFMA: H1 = x @ W1, half-major [2][(N+1)][32] fp16
__global__ __launch_bounds__(256) void k_gemm1(
    const float* __restrict__ A, const unsigned short* __restrict__ Wfrag,
    unsigned short* __restrict__ H, int n) {
  const int lane = threadIdx.x & 63;
  const int wv = threadIdx.x >> 6;
  const int r0 = blockIdx.x * 64 + wv * 16;

  const int brow = r0 + (lane & 15);
  const int browc = brow < n ? brow : n - 1;
  const float* xrow = A + (size_t)browc * 128 + (lane >> 4) * 8;
  const size_t H1S = (size_t)(n + 1) * 32;

  f32x4 acc[4] = {};
#pragma unroll
  for (int kb = 0; kb < 4; ++kb) {
    float4 p = *(const float4*)(xrow + kb * 32);
    float4 q = *(const float4*)(xrow + kb * 32 + 4);
    half8 xf;
    xf[0] = (_Float16)p.x; xf[1] = (_Float16)p.y;
    xf[2] = (_Float16)p.z; xf[3] = (_Float16)p.w;
    xf[4] = (_Float16)q.x; xf[5] = (_Float16)q.y;
    xf[6] = (_Float16)q.z; xf[7] = (_Float16)q.w;
#pragma unroll
    for (int nt = 0; nt < 4; ++nt) {
      half8 wf = *(const half8*)&Wfrag[(size_t)((nt * 4 + kb) * 64 + lane) * 8];
      acc[nt] = __builtin_amdgcn_mfma_f32_16x16x32_f16(wf, xf, acc[nt], 0, 0, 0);
    }
  }
  const int orow = r0 + (lane & 15);
  if (orow < n) {
#pragma unroll
    for (int nt = 0; nt < 4; ++nt) {
      int col = nt * 16 + (lane >> 4) * 4;
      int half = col >> 5, c32 = col & 31;
      uint2 o;
      o.x = f2h2(acc[nt][0], acc[nt][1]);
      o.y = f2h2(acc[nt][2], acc[nt][3]);
      *(uint2*)&H[(size_t)half * H1S + (size_t)orow * 32 + c32] = o;
    }
  }
}

// ---------------------------------------------------------------- half-hop at 32 dims (64B rows = 1 cache line)
// one wave per node; 8 subgroups of 8 lanes; lane loads uint2 (4 dims).
// 32 edge indices preloaded (pad = zero row n); tail for deg > 32.
__device__ __forceinline__ void hop32_gather(const unsigned short* __restrict__ hs,
    const int* __restrict__ csr, int beg, int end, int sub, int t, int npad,
    unsigned int& a01, unsigned int& a23) {
  a01 = 0u; a23 = 0u;
  int idx[4];
#pragma unroll
  for (int k = 0; k < 4; ++k) {
    int a = beg + k * 8 + sub;
    idx[k] = (a < end) ? csr[a] : npad;
  }
  uint2 v[4];
#pragma unroll
  for (int k = 0; k < 4; ++k)
    v[k] = *(const uint2*)&hs[(size_t)idx[k] * 32 + 4 * t];
#pragma unroll
  for (int k = 0; k < 4; ++k) {
    a01 = hadd2(a01, v[k].x);
    a23 = hadd2(a23, v[k].y);
  }
  for (int eb = beg + 32; eb < end; eb += 8) {   // rare tail (P ~ 1e-4)
    int a = eb + sub;
    int j = (a < end) ? csr[a] : npad;
    uint2 w = *(const uint2*)&hs[(size_t)j * 32 + 4 * t];
    a01 = hadd2(a01, w.x);
    a23 = hadd2(a23, w.y);
  }
}

__global__ __launch_bounds__(256) void k_hop32(const unsigned short* __restrict__ hin,
    unsigned short* __restrict__ hout, const int* __restrict__ offs,
    const int* __restrict__ csr, int n) {
  int wid = (blockIdx.x * 256 + threadIdx.x) >> 6;
  if (wid >= n) return;
  int lane = threadIdx.x & 63;
  int sub = lane >> 3, t = lane & 7;
  int beg = offs[wid], end = offs[wid + 1];
  unsigned int a01, a23;
  hop32_gather(hin, csr, beg, end, sub, t, n, a01, a23);
  a01 = hadd2(a01, (unsigned int)__shfl_down((int)a01, 32, 64));
  a23 = hadd2(a23, (unsigned int)__shfl_down((int)a23, 32, 64));
  a01 = hadd2(a01, (unsigned int)__shfl_down((int)a01, 16, 64));
  a23 = hadd2(a23, (unsigned int)__shfl_down((int)a23, 16, 64));
  a01 = hadd2(a01, (unsigned int)__shfl_down((int)a01, 8, 64));
  a23 = hadd2(a23, (unsigned int)__shfl_down((int)a23, 8, 64));
  if (sub == 0) {
    uint2 sv = *(const uint2*)&hin[(size_t)wid * 32 + 4 * t];
    uint2 o;
    o.x = hadd2(a01, sv.x);
    o.y = hadd2(a23, sv.y);
    *(uint2*)&hout[(size_t)wid * 32 + 4 * t] = o;
  }
}

// hop2 half: fused per-column (sum, sumsq) stats for this half's 32 dims
__global__ __launch_bounds__(256) void k_hop32_stats(const unsigned short* __restrict__ hin,
    unsigned short* __restrict__ hout, const int* __restrict__ offs,
    const int* __restrict__ csr, float* __restrict__ stats, int n, int half) {
  int wid = (blockIdx.x * 256 + threadIdx.x) >> 6;
  int lane = threadIdx.x & 63;
  int sub = lane >> 3, t = lane & 7;
  float f0 = 0.f, f1 = 0.f, f2 = 0.f, f3 = 0.f;
  if (wid < n) {
    int beg = offs[wid], end = offs[wid + 1];
    unsigned int a01, a23;
    hop32_gather(hin, csr, beg, end, sub, t, n, a01, a23);
    a01 = hadd2(a01, (unsigned int)__shfl_down((int)a01, 32, 64));
    a23 = hadd2(a23, (unsigned int)__shfl_down((int)a23, 32, 64));
    a01 = hadd2(a01, (unsigned int)__shfl_down((int)a01, 16, 64));
    a23 = hadd2(a23, (unsigned int)__shfl_down((int)a23, 16, 64));
    a01 = hadd2(a01, (unsigned int)__shfl_down((int)a01, 8, 64));
    a23 = hadd2(a23, (unsigned int)__shfl_down((int)a23, 8, 64));
    if (sub == 0) {
      uint2 sv = *(const uint2*)&hin[(size_t)wid * 32 + 4 * t];
      uint2 o;
      o.x = hadd2(a01, sv.x);
      o.y = hadd2(a23, sv.y);
      *(uint2*)&hout[(size_t)wid * 32 + 4 * t] = o;
      float2 p01 = h22f2(o.x), p23 = h22f2(o.y);
      f0 = p01.x; f1 = p01.y; f2 = p23.x; f3 = p23.y;
    }
  }
  __shared__ float l1[4][32];
  __shared__ float l2[4][32];
  const int w = threadIdx.x >> 6;
  if (sub == 0) {
    if (wid >= n) { f0 = f1 = f2 = f3 = 0.f; }
    *(float4*)&l1[w][4 * t] = make_float4(f0, f1, f2, f3);
    *(float4*)&l2[w][4 * t] = make_float4(f0 * f0, f1 * f1, f2 * f2, f3 * f3);
  }
  __syncthreads();
  if (threadIdx.x < 32) {
    int i = threadIdx.x;
    float t1 = l1[0][i] + l1[1][i] + l1[2][i] + l1[3][i];
    float t2 = l2[0][i] + l2[1][i] + l2[2][i] + l2[3][i];
    float* slot = stats + (size_t)(blockIdx.x & (NSLOT - 1)) * 128;
    atomicAdd(&slot[half * 32 + i], t1);
    atomicAdd(&slot[64 + half * 32 + i], t2);
  }
}

__global__ void k_finalize_stats(const float* __restrict__ stats,
    const float* __restrict__ bn_w, const float* __restrict__ bn_b,
    float* __restrict__ ab, int n) {
  int f = threadIdx.x;
  if (f < 64) {
    float s1 = 0.f, s2 = 0.f;
#pragma unroll 4
    for (int j = 0; j < NSLOT; ++j) {
      s1 += stats[(size_t)j * 128 + f];
      s2 += stats[(size_t)j * 128 + 64 + f];
    }
    float inv_n = 1.0f / (float)n;
    float mu = s1 * inv_n;
    float var = s2 * inv_n - mu * mu;
    float s = bn_w[f] * rsqrtf(var + 1e-5f);
    ab[f] = s;
    ab[64 + f] = bn_b[f] - mu * s;
  }
}

// ---------------------------------------------------------------- GEMM2 (half-major fp16 in) + BN affine + SELU -> Y fp16 (Nx16)
__global__ __launch_bounds__(256) void k_gemm2(const unsigned short* __restrict__ A,
    const float* __restrict__ ab, const float* __restrict__ W2,
    unsigned short* __restrict__ Y, int n) {
  int row = blockIdx.x * 256 + threadIdx.x;
  if (row >= n) return;
  const size_t H3S = (size_t)n * 32;
  float4 acc0 = make_float4(0, 0, 0, 0), acc1 = acc0, acc2 = acc0, acc3 = acc0;
#pragma unroll
  for (int kb = 0; kb < 8; ++kb) {
    int half = kb >> 2;
    uint4 a = *(const uint4*)&A[(size_t)half * H3S + (size_t)row * 32 + (kb & 3) * 8];
    unsigned int pk[4] = {a.x, a.y, a.z, a.w};
#pragma unroll
    for (int q = 0; q < 4; ++q) {
      float2 f2v = h22f2(pk[q]);
#pragma unroll
      for (int h = 0; h < 2; ++h) {
        int k = kb * 8 + 2 * q + h;
        float f = h ? f2v.y : f2v.x;
        float y = ab[k] * f + ab[64 + k];
        y = y > 0.f ? SELU_LAMBDA * y : SELU_LAMBDA * SELU_ALPHA * expm1f(y);
        const float4* Wr = (const float4*)&W2[k * 16];
        float4 w0 = Wr[0], w1 = Wr[1], w2 = Wr[2], w3 = Wr[3];
        acc0.x += y * w0.x; acc0.y += y * w0.y; acc0.z += y * w0.z; acc0.w += y * w0.w;
        acc1.x += y * w1.x; acc1.y += y * w1.y; acc1.z += y * w1.z; acc1.w += y * w1.w;
        acc2.x += y * w2.x; acc2.y += y * w2.y; acc2.z += y * w2.z; acc2.w += y * w2.w;
        acc3.x += y * w3.x; acc3.y += y * w3.y; acc3.z += y * w3.z; acc3.w += y * w3.w;
      }
    }
  }
  uint4 o;
  o.x = f2h2(acc0.x, acc0.y); o.y = f2h2(acc0.z, acc0.w);
  o.z = f2h2(acc1.x, acc1.y); o.w = f2h2(acc1.z, acc1.w);
  uint4 o2;
  o2.x = f2h2(acc2.x, acc2.y); o2.y = f2h2(acc2.z, acc2.w);
  o2.z = f2h2(acc3.x, acc3.y); o2.w = f2h2(acc3.z, acc3.w);
  uint4* op = (uint4*)(Y + (size_t)row * 16);
  op[0] = o;
  op[1] = o2;
}

// ---------------------------------------------------------------- hop at D=16 (fp16) + b2 + log_softmax
// one wave per node; 16 subgroups x 4 lanes; lane loads uint2 (4 dims)
// -> 16 edges per gather instruction; 32 edges preloaded; pad = zero row n.
__global__ __launch_bounds__(256) void k_hop16(const unsigned short* __restrict__ Y,
    const float* __restrict__ b2, float* __restrict__ out,
    const int* __restrict__ offs, const int* __restrict__ csr, int n) {
  int wid = (blockIdx.x * 256 + threadIdx.x) >> 6;
  if (wid >= n) return;
  int lane = threadIdx.x & 63;
  int sub = lane >> 2, t = lane & 3;   // lane covers dims 4t..4t+3
  int beg = offs[wid], end = offs[wid + 1];
  int i0, i1;
  {
    int a0i = beg + sub, a1i = beg + 16 + sub;
    i0 = (a0i < end) ? csr[a0i] : n;
    i1 = (a1i < end) ? csr[a1i] : n;
  }
  uint2 v0 = *(const uint2*)&Y[(size_t)i0 * 16 + 4 * t];
  uint2 v1 = *(const uint2*)&Y[(size_t)i1 * 16 + 4 * t];
  unsigned int a01 = hadd2(v0.x, v1.x);
  unsigned int a23 = hadd2(v0.y, v1.y);
  for (int eb = beg + 32; eb < end; eb += 16) {   // rare tail
    int a = eb + sub;
    int idx = (a < end) ? csr[a] : n;
    uint2 w = *(const uint2*)&Y[(size_t)idx * 16 + 4 * t];
    a01 = hadd2(a01, w.x);
    a23 = hadd2(a23, w.y);
  }
  a01 = hadd2(a01, (unsigned int)__shfl_down((int)a01, 32, 64));
  a23 = hadd2(a23, (unsigned int)__shfl_down((int)a23, 32, 64));
  a01 = hadd2(a01, (unsigned int)__shfl_down((int)a01, 16, 64));
  a23 = hadd2(a23, (unsigned int)__shfl_down((int)a23, 16, 64));
  a01 = hadd2(a01, (unsigned int)__shfl_down((int)a01, 8, 64));
  a23 = hadd2(a23, (unsigned int)__shfl_down((int)a23, 8, 64));
  a01 = hadd2(a01, (unsigned int)__shfl_down((int)a01, 4, 64));
  a23 = hadd2(a23, (unsigned int)__shfl_down((int)a23, 4, 64));
  if (sub == 0) {
    uint2 sv = *(const uint2*)&Y[(size_t)wid * 16 + 4 * t];
    float2 s01 = h22f2(sv.x), s23 = h22f2(sv.y);
    float2 p01 = h22f2(a01), p23 = h22f2(a23);
    float4 bb = *(const float4*)&b2[4 * t];
    float v0f = p01.x + s01.x + bb.x;
    float v1f = p01.y + s01.y + bb.y;
    float v2f = p23.x + s23.x + bb.z;
    float v3f = p23.y + s23.y + bb.w;
    float m = fmaxf(fmaxf(v0f, v1f), fmaxf(v2f, v3f));
    m = fmaxf(m, __shfl_xor(m, 1, 4));
    m = fmaxf(m, __shfl_xor(m, 2, 4));
    float s = expf(v0f - m) + expf(v1f - m) + expf(v2f - m) + expf(v3f - m);
    s += __shfl_xor(s, 1, 4);
    s += __shfl_xor(s, 2, 4);
    float ls = m + logf(s);
    *(float4*)&out[(size_t)wid * 16 + 4 * t] =
        make_float4(v0f - ls, v1f - ls, v2f - ls, v3f - ls);
  }
}

// ---------------------------------------------------------------- launch
extern "C" void kernel_launch(void* const* d_in, const int* in_sizes, int n_in,
                              void* d_out, int out_size, void* d_ws, size_t ws_size,
                              hipStream_t stream) {
  const float* x   = (const float*)d_in[0];
  const int* esrc  = (const int*)d_in[1];
  const int* edst  = (const int*)d_in[2];
  const float* W1  = (const float*)d_in[3];
  // d_in[4] = b1: cancels exactly under batchnorm mean subtraction
  const float* bnw = (const float*)d_in[5];
  const float* bnb = (const float*)d_in[6];
  const float* W2  = (const float*)d_in[7];
  const float* b2  = (const float*)d_in[8];
  float* out = (float*)d_out;

  const int N = in_sizes[0] / 128;  // 100000
  const int E = in_sizes[1];        // 1600000
  const int NB = (N + BNODES - 1) >> BSHIFT;  // 196 buckets

  char* p = (char*)d_ws;
  auto alloc = [&](size_t bytes) {
    char* q = p;
    p += (bytes + 255) & ~(size_t)255;
    return q;
  };
  int* cursor  = (int*)alloc(256 * sizeof(int));
  int* binned  = (int*)alloc((size_t)NB * CAP * sizeof(int));
  int* offs    = (int*)alloc((size_t)(N + 4) * sizeof(int));
  int* csr     = (int*)alloc((size_t)E * sizeof(int));
  float* stats = (float*)alloc((size_t)NSLOT * 128 * sizeof(float));
  float* ab    = (float*)alloc(128 * sizeof(float));
  unsigned short* Wfrag = (unsigned short*)alloc(1024 * 8 * sizeof(unsigned short));
  const size_t H1S = (size_t)(N + 1) * 32;   // per-half stride (padded)
  unsigned short* h1 = (unsigned short*)alloc(2 * H1S * sizeof(unsigned short));
  unsigned short* h2 = (unsigned short*)alloc(2 * H1S * sizeof(unsigned short));
  unsigned short* h3 = (unsigned short*)alloc((size_t)2 * N * 32 * sizeof(unsigned short));
  unsigned short* Yb = (unsigned short*)alloc((size_t)(N + 1) * 16 * sizeof(unsigned short));

  // setup: zero cursor/stats/pad rows + build W1 fragments (one dispatch)
  k_setup<<<32, 256, 0, stream>>>(cursor, stats, h1, h2, Yb, W1, Wfrag, N);

  // CSR build
  k_bin<<<(E + CHUNK - 1) / CHUNK, 256, 0, stream>>>(esrc, edst, cursor, binned, E);
  k_build<<<NB, 256, 0, stream>>>(binned, cursor, offs, csr, N, NB, E);

  // GEMM first; hops run at 32 dims per pass (64B rows), halves independent
  k_gemm1<<<(N + 63) / 64, 256, 0, stream>>>(x, Wfrag, h1, N);

  int hopBlocks = (N * 64 + 255) / 256;  // one wave per node
  const size_t H3S = (size_t)N * 32;
  // half 0: hop1 then hop2 (write-then-gather keeps the half L2-warm)
  k_hop32<<<hopBlocks, 256, 0, stream>>>(h1, h2, offs, csr, N);
  k_hop32_stats<<<hopBlocks, 256, 0, stream>>>(h2, h3, offs, csr, stats, N, 0);
  // half 1
  k_hop32<<<hopBlocks, 256, 0, stream>>>(h1 + H1S, h2 + H1S, offs, csr, N);
  k_hop32_stats<<<hopBlocks, 256, 0, stream>>>(h2 + H1S, h3 + H3S, offs, csr, stats, N, 1);

  k_finalize_stats<<<1, 64, 0, stream>>>(stats, bnw, bnb, ab, N);

  // GEMM2 (with fused BN+SELU) before the last hop: hop runs at D=16 fp16
  k_gemm2<<<(N + 255) / 256, 256, 0, stream>>>(h3, ab, W2, Yb, N);
  k_hop16<<<hopBlocks, 256, 0, stream>>>(Yb, b2, out, offs, csr, N);
}

// Round 15
// 184.398 us; speedup vs baseline: 1.4154x; 1.4154x over previous
//
#include <hip/hip_runtime.h>
#include <hip/hip_fp16.h>
#include <math.h>

#define SELU_LAMBDA 1.0507009873554805f
#define SELU_ALPHA  1.6732632423543772f

#define BSHIFT 9
#define BNODES 512          // nodes per bucket
#define CAP    10240        // bucket capacity (mean 8192, +22 sigma)
#define CHUNK  4096         // edges per k_bin block
#define NSLOT  64           // stats atomic spreading slots

typedef _Float16 half8 __attribute__((ext_vector_type(8)));
typedef float f32x4 __attribute__((ext_vector_type(4)));

// fp16 helpers
__device__ __forceinline__ unsigned int f2h2(float a, float b) {
  __half2 h = __floats2half2_rn(a, b);
  return *(unsigned int*)&h;
}
__device__ __forceinline__ float2 h22f2(unsigned int u) {
  __half2 h = *(__half2*)&u;
  return __half22float2(h);
}
__device__ __forceinline__ unsigned int hadd2(unsigned int a, unsigned int b) {
  __half2 x = *(__half2*)&a, y = *(__half2*)&b;
  __half2 r = __hadd2(x, y);
  return *(unsigned int*)&r;
}

// ---------------------------------------------------------------- setup: zero cursor/stats/pads + W1/W2 MFMA-fragment prep
__global__ __launch_bounds__(256) void k_setup(int* __restrict__ cursor,
    float* __restrict__ stats, unsigned short* __restrict__ h1pad,
    unsigned short* __restrict__ h2pad, unsigned short* __restrict__ ybpad,
    const float* __restrict__ W1, unsigned short* __restrict__ Wfrag,
    const float* __restrict__ W2, unsigned short* __restrict__ W2frag) {
  int i = blockIdx.x * 256 + threadIdx.x;
  if (i < 256) cursor[i] = 0;
  if (i < NSLOT * 128) stats[i] = 0.f;
  if (i < 64) { h1pad[i] = 0; h2pad[i] = 0; }
  if (i < 16) ybpad[i] = 0;
  if (i < 1024) {  // Wfrag[(ntile*4+kb)*64+lane][8]: W1[k0+j][ntile*16+(lane&15)]
    int lane = i & 63;
    int kb = (i >> 6) & 3;
    int ntile = i >> 8;
    int k0 = kb * 32 + (lane >> 4) * 8;
    int col = ntile * 16 + (lane & 15);
    unsigned short tmp[8];
#pragma unroll
    for (int j = 0; j < 8; ++j) {
      __half h = __float2half_rn(W1[(size_t)(k0 + j) * 64 + col]);
      tmp[j] = *(unsigned short*)&h;
    }
    *(uint4*)&Wfrag[(size_t)i * 8] = *(uint4*)tmp;
  }
  if (i < 128) {   // W2frag[kb*64+lane][8]: W2[k0+j][lane&15]
    int lane = i & 63;
    int kb = i >> 6;
    int k0 = kb * 32 + (lane >> 4) * 8;
    int col = lane & 15;
    unsigned short tmp[8];
#pragma unroll
    for (int j = 0; j < 8; ++j) {
      __half h = __float2half_rn(W2[(size_t)(k0 + j) * 16 + col]);
      tmp[j] = *(unsigned short*)&h;
    }
    *(uint4*)&W2frag[(size_t)i * 8] = *(uint4*)tmp;
  }
}

// ---------------------------------------------------------------- fused: bin edges (blocks < nbin) + MFMA GEMM1 (rest)
// bin: packed entry src | (dstLocal << 17); gemm1: H1 = x @ W1 fp16
__global__ __launch_bounds__(256) void k_bin_gemm1(const int* __restrict__ src,
    const int* __restrict__ dst, int* __restrict__ cursor,
    int* __restrict__ binned, int e, int nbin,
    const float* __restrict__ A, const unsigned short* __restrict__ Wfrag,
    unsigned short* __restrict__ H, int n) {
  if ((int)blockIdx.x < nbin) {
    __shared__ int hist[256];
    __shared__ int gb[256];
    const int tid = threadIdx.x;
    hist[tid] = 0;
    __syncthreads();
    const int base = blockIdx.x * CHUNK;
    int bk[16], rk[16], pk[16];
#pragma unroll
    for (int k = 0; k < 16; ++k) {
      int i = base + k * 256 + tid;
      if (i < e) {
        int d = dst[i];
        int s = src[i];
        int b = d >> BSHIFT;
        bk[k] = b;
        pk[k] = s | ((d & (BNODES - 1)) << 17);
        rk[k] = atomicAdd(&hist[b], 1);
      } else {
        bk[k] = -1;
      }
    }
    __syncthreads();
    int h = hist[tid];
    if (h > 0) gb[tid] = atomicAdd(&cursor[tid], h);
    __syncthreads();
#pragma unroll
    for (int k = 0; k < 16; ++k) {
      if (bk[k] >= 0) binned[bk[k] * CAP + gb[bk[k]] + rk[k]] = pk[k];
    }
    return;
  }
  // ---- gemm1 part
  const int gblk = blockIdx.x - nbin;
  const int lane = threadIdx.x & 63;
  const int wv = threadIdx.x >> 6;
  const int r0 = gblk * 64 + wv * 16;

  const int brow = r0 + (lane & 15);
  const int browc = brow < n ? brow : n - 1;
  const float* xrow = A + (size_t)browc * 128 + (lane >> 4) * 8;

  f32x4 acc[4] = {};
#pragma unroll
  for (int kb = 0; kb < 4; ++kb) {
    float4 p = *(const float4*)(xrow + kb * 32);
    float4 q = *(const float4*)(xrow + kb * 32 + 4);
    half8 xf;
    xf[0] = (_Float16)p.x; xf[1] = (_Float16)p.y;
    xf[2] = (_Float16)p.z; xf[3] = (_Float16)p.w;
    xf[4] = (_Float16)q.x; xf[5] = (_Float16)q.y;
    xf[6] = (_Float16)q.z; xf[7] = (_Float16)q.w;
#pragma unroll
    for (int nt = 0; nt < 4; ++nt) {
      half8 wf = *(const half8*)&Wfrag[(size_t)((nt * 4 + kb) * 64 + lane) * 8];
      acc[nt] = __builtin_amdgcn_mfma_f32_16x16x32_f16(wf, xf, acc[nt], 0, 0, 0);
    }
  }
  const int orow = r0 + (lane & 15);
  if (orow < n) {
#pragma unroll
    for (int nt = 0; nt < 4; ++nt) {
      int col = nt * 16 + (lane >> 4) * 4;
      uint2 o;
      o.x = f2h2(acc[nt][0], acc[nt][1]);
      o.y = f2h2(acc[nt][2], acc[nt][3]);
      *(uint2*)&H[(size_t)orow * 64 + col] = o;
    }
  }
}

// ---------------------------------------------------------------- phase 2: per-bucket CSR build
__global__ __launch_bounds__(256) void k_build(const int* __restrict__ binned,
    const int* __restrict__ cursor, int* __restrict__ offs,
    int* __restrict__ csr, int n, int nb, int etot) {
  __shared__ int sc[2][256];
  __shared__ int deg[BNODES];
  __shared__ int pre[BNODES];
  __shared__ int wsum[4];
  __shared__ int stage[CAP];
  __shared__ int s_cbase;
  const int b = blockIdx.x;
  const int tid = threadIdx.x;

  int v0 = (tid < nb) ? cursor[tid] : 0;
  sc[0][tid] = v0;
  __syncthreads();
  int cur = 0;
  for (int d = 1; d < 256; d <<= 1) {
    int t = sc[cur][tid];
    if (tid >= d) t += sc[cur][tid - d];
    sc[cur ^ 1][tid] = t;
    cur ^= 1;
    __syncthreads();
  }
  if (tid == 0) {
    s_cbase = (b == 0) ? 0 : sc[cur][b - 1];
    if (b == 0) offs[n] = etot;
  }
  deg[tid] = 0;
  deg[tid + 256] = 0;
  __syncthreads();
  const int cbase = s_cbase;
  const int cnt = sc[cur][b] - cbase;

  const int nodeBase = b << BSHIFT;
  const int* gsrc = binned + b * CAP;

  for (int i = tid; i < cnt; i += 256) atomicAdd(&deg[gsrc[i] >> 17], 1);
  __syncthreads();

  const int lane = tid & 63, w = tid >> 6;
  int a0 = deg[2 * tid], a1 = deg[2 * tid + 1];
  int ps = a0 + a1;
  int s = ps;
#pragma unroll
  for (int d = 1; d < 64; d <<= 1) {
    int t = __shfl_up(s, d, 64);
    if (lane >= d) s += t;
  }
  if (lane == 63) wsum[w] = s;
  __syncthreads();
  if (tid == 0) {
    int acc = 0;
#pragma unroll
    for (int j = 0; j < 4; ++j) { int t = wsum[j]; wsum[j] = acc; acc += t; }
  }
  __syncthreads();
  int ex = wsum[w] + s - ps;
  pre[2 * tid] = ex;
  pre[2 * tid + 1] = ex + a0;
  deg[tid] = 0;
  deg[tid + 256] = 0;
  __syncthreads();

  const int nNodes = min(BNODES, n - nodeBase);
  for (int i = tid; i < nNodes; i += 256) offs[nodeBase + i] = cbase + pre[i];

  for (int i = tid; i < cnt; i += 256) {
    int v = gsrc[i];
    int dl = v >> 17;
    int p = pre[dl] + atomicAdd(&deg[dl], 1);
    stage[p] = v & 0x1FFFF;
  }
  __syncthreads();
  for (int i = tid; i < cnt; i += 256) csr[cbase + i] = stage[i];
}

// ---------------------------------------------------------------- hop at D=64 (fp16 in/out)
// one wave per node; 4 sub-groups of 16 lanes; lane loads 4 dims (8B).
// All 32 edge indices preloaded (pad = zero row n); tail for deg > 32.
__device__ __forceinline__ void hop64_gather32(const unsigned short* __restrict__ hin,
    const int* __restrict__ csr, int beg, int end, int sub, int t, int npad,
    unsigned int& a01, unsigned int& a23) {
  a01 = 0u; a23 = 0u;
  int idx[8];
#pragma unroll
  for (int k = 0; k < 8; ++k) {
    int a = beg + k * 4 + sub;
    idx[k] = (a < end) ? csr[a] : npad;
  }
  uint2 v[8];
#pragma unroll
  for (int k = 0; k < 8; ++k)
    v[k] = *(const uint2*)&hin[(size_t)idx[k] * 64 + 4 * t];
#pragma unroll
  for (int k = 0; k < 8; ++k) {
    a01 = hadd2(a01, v[k].x);
    a23 = hadd2(a23, v[k].y);
  }
  for (int eb = beg + 32; eb < end; eb += 16) {   // rare tail (P ~ 1e-4)
    int jx[4];
#pragma unroll
    for (int k = 0; k < 4; ++k) {
      int a = eb + k * 4 + sub;
      jx[k] = (a < end) ? csr[a] : npad;
    }
    uint2 w[4];
#pragma unroll
    for (int k = 0; k < 4; ++k)
      w[k] = *(const uint2*)&hin[(size_t)jx[k] * 64 + 4 * t];
#pragma unroll
    for (int k = 0; k < 4; ++k) {
      a01 = hadd2(a01, w[k].x);
      a23 = hadd2(a23, w[k].y);
    }
  }
}

__global__ __launch_bounds__(256) void k_hop64b(const unsigned short* __restrict__ hin,
    unsigned short* __restrict__ hout, const int* __restrict__ offs,
    const int* __restrict__ csr, int n) {
  int wid = (blockIdx.x * 256 + threadIdx.x) >> 6;
  if (wid >= n) return;
  int lane = threadIdx.x & 63;
  int sub = lane >> 4, t = lane & 15;
  int beg = offs[wid], end = offs[wid + 1];
  unsigned int a01, a23;
  hop64_gather32(hin, csr, beg, end, sub, t, n, a01, a23);
  a01 = hadd2(a01, (unsigned int)__shfl_down((int)a01, 32, 64));
  a23 = hadd2(a23, (unsigned int)__shfl_down((int)a23, 32, 64));
  a01 = hadd2(a01, (unsigned int)__shfl_down((int)a01, 16, 64));
  a23 = hadd2(a23, (unsigned int)__shfl_down((int)a23, 16, 64));
  if (sub == 0) {
    uint2 sv = *(const uint2*)&hin[(size_t)wid * 64 + 4 * t];
    uint2 o;
    o.x = hadd2(a01, sv.x);
    o.y = hadd2(a23, sv.y);
    *(uint2*)&hout[(size_t)wid * 64 + 4 * t] = o;
  }
}

// hop2: fp16 in/out, fused per-column (sum, sumsq) batch stats (fp32 epilogue)
__global__ __launch_bounds__(256) void k_hop64b_stats(const unsigned short* __restrict__ hin,
    unsigned short* __restrict__ hout, const int* __restrict__ offs,
    const int* __restrict__ csr, float* __restrict__ stats, int n) {
  int wid = (blockIdx.x * 256 + threadIdx.x) >> 6;
  int lane = threadIdx.x & 63;
  int sub = lane >> 4, t = lane & 15;
  float f0 = 0.f, f1 = 0.f, f2 = 0.f, f3 = 0.f;
  if (wid < n) {
    int beg = offs[wid], end = offs[wid + 1];
    unsigned int a01, a23;
    hop64_gather32(hin, csr, beg, end, sub, t, n, a01, a23);
    a01 = hadd2(a01, (unsigned int)__shfl_down((int)a01, 32, 64));
    a23 = hadd2(a23, (unsigned int)__shfl_down((int)a23, 32, 64));
    a01 = hadd2(a01, (unsigned int)__shfl_down((int)a01, 16, 64));
    a23 = hadd2(a23, (unsigned int)__shfl_down((int)a23, 16, 64));
    if (sub == 0) {
      uint2 sv = *(const uint2*)&hin[(size_t)wid * 64 + 4 * t];
      uint2 o;
      o.x = hadd2(a01, sv.x);
      o.y = hadd2(a23, sv.y);
      *(uint2*)&hout[(size_t)wid * 64 + 4 * t] = o;
      float2 p01 = h22f2(o.x), p23 = h22f2(o.y);
      f0 = p01.x; f1 = p01.y; f2 = p23.x; f3 = p23.y;
    }
  }
  __shared__ float l1[4][64];
  __shared__ float l2[4][64];
  const int w = threadIdx.x >> 6;
  if (sub == 0) {
    *(float4*)&l1[w][4 * t] = make_float4(f0, f1, f2, f3);
    *(float4*)&l2[w][4 * t] = make_float4(f0 * f0, f1 * f1, f2 * f2, f3 * f3);
  }
  __syncthreads();
  if (threadIdx.x < 64) {
    float t1 = l1[0][threadIdx.x] + l1[1][threadIdx.x] + l1[2][threadIdx.x] + l1[3][threadIdx.x];
    float t2 = l2[0][threadIdx.x] + l2[1][threadIdx.x] + l2[2][threadIdx.x] + l2[3][threadIdx.x];
    float* slot = stats + (size_t)(blockIdx.x & (NSLOT - 1)) * 128;
    atomicAdd(&slot[threadIdx.x], t1);
    atomicAdd(&slot[64 + threadIdx.x], t2);
  }
}

__global__ void k_finalize_stats(const float* __restrict__ stats,
    const float* __restrict__ bn_w, const float* __restrict__ bn_b,
    float* __restrict__ ab, int n) {
  int f = threadIdx.x;
  if (f < 64) {
    float s1 = 0.f, s2 = 0.f;
#pragma unroll 4
    for (int j = 0; j < NSLOT; ++j) {
      s1 += stats[(size_t)j * 128 + f];
      s2 += stats[(size_t)j * 128 + 64 + f];
    }
    float inv_n = 1.0f / (float)n;
    float mu = s1 * inv_n;
    float var = s2 * inv_n - mu * mu;
    float s = bn_w[f] * rsqrtf(var + 1e-5f);
    ab[f] = s;
    ab[64 + f] = bn_b[f] - mu * s;
  }
}

// ---------------------------------------------------------------- GEMM2 via MFMA: Y = selu(bn(h3)) @ W2 -> fp16 (Nx16)
// wave = 16 rows; B-frag = selu(bn(h3-row)) 8 dims/lane; A-frag = W2frag.
__global__ __launch_bounds__(256) void k_gemm2(const unsigned short* __restrict__ A,
    const float* __restrict__ ab, const unsigned short* __restrict__ W2frag,
    unsigned short* __restrict__ Y, int n) {
  const int lane = threadIdx.x & 63;
  const int wv = threadIdx.x >> 6;
  const int r0 = blockIdx.x * 64 + wv * 16;
  const int brow = r0 + (lane & 15);
  const int browc = brow < n ? brow : n - 1;
  const int kbase = (lane >> 4) * 8;

  f32x4 acc = {};
#pragma unroll
  for (int kb = 0; kb < 2; ++kb) {
    int k0 = kb * 32 + kbase;
    uint4 a = *(const uint4*)&A[(size_t)browc * 64 + k0];
    unsigned int pk[4] = {a.x, a.y, a.z, a.w};
    half8 yf;
#pragma unroll
    for (int q = 0; q < 4; ++q) {
      float2 f2v = h22f2(pk[q]);
      float s0 = ab[k0 + 2 * q], sh0 = ab[64 + k0 + 2 * q];
      float s1 = ab[k0 + 2 * q + 1], sh1 = ab[64 + k0 + 2 * q + 1];
      float y0 = s0 * f2v.x + sh0;
      float y1 = s1 * f2v.y + sh1;
      y0 = y0 > 0.f ? SELU_LAMBDA * y0 : SELU_LAMBDA * SELU_ALPHA * expm1f(y0);
      y1 = y1 > 0.f ? SELU_LAMBDA * y1 : SELU_LAMBDA * SELU_ALPHA * expm1f(y1);
      yf[2 * q] = (_Float16)y0;
      yf[2 * q + 1] = (_Float16)y1;
    }
    half8 wf = *(const half8*)&W2frag[(size_t)(kb * 64 + lane) * 8];
    acc = __builtin_amdgcn_mfma_f32_16x16x32_f16(wf, yf, acc, 0, 0, 0);
  }
  const int orow = r0 + (lane & 15);
  if (orow < n) {
    uint2 o;
    o.x = f2h2(acc[0], acc[1]);
    o.y = f2h2(acc[2], acc[3]);
    *(uint2*)&Y[(size_t)orow * 16 + (lane >> 4) * 4] = o;
  }
}

// ---------------------------------------------------------------- hop at D=16 (fp16 in) + b2 + log_softmax
// one wave per node; 8 subgroups x 8 lanes; lane loads uint (2 dims, half2)
// 24 edge indices preloaded (3 gathers in flight); tail for deg > 24 (P~2%).
__global__ __launch_bounds__(256) void k_hop16(const unsigned short* __restrict__ Y,
    const float* __restrict__ b2, float* __restrict__ out,
    const int* __restrict__ offs, const int* __restrict__ csr, int n) {
  int wid = (blockIdx.x * 256 + threadIdx.x) >> 6;
  if (wid >= n) return;
  int lane = threadIdx.x & 63;
  int sub = lane >> 3, t = lane & 7;   // lane covers dims 2t, 2t+1
  int beg = offs[wid], end = offs[wid + 1];
  int i0, i1, i2;
  {
    int a0i = beg + sub, a1i = beg + 8 + sub, a2i = beg + 16 + sub;
    i0 = (a0i < end) ? csr[a0i] : n;
    i1 = (a1i < end) ? csr[a1i] : n;
    i2 = (a2i < end) ? csr[a2i] : n;
  }
  unsigned int v0 = *(const unsigned int*)&Y[(size_t)i0 * 16 + 2 * t];
  unsigned int v1 = *(const unsigned int*)&Y[(size_t)i1 * 16 + 2 * t];
  unsigned int v2 = *(const unsigned int*)&Y[(size_t)i2 * 16 + 2 * t];
  unsigned int accp = hadd2(hadd2(v0, v1), v2);
  for (int eb = beg + 24; eb < end; eb += 8) {
    int a = eb + sub;
    int idx = (a < end) ? csr[a] : n;
    accp = hadd2(accp, *(const unsigned int*)&Y[(size_t)idx * 16 + 2 * t]);
  }
  float2 pf = h22f2(accp);
  float a0 = pf.x, a1 = pf.y;
  a0 += __shfl_down(a0, 32, 64); a1 += __shfl_down(a1, 32, 64);
  a0 += __shfl_down(a0, 16, 64); a1 += __shfl_down(a1, 16, 64);
  a0 += __shfl_down(a0, 8, 64);  a1 += __shfl_down(a1, 8, 64);
  if (sub == 0) {
    float2 sf = h22f2(*(const unsigned int*)&Y[(size_t)wid * 16 + 2 * t]);
    float2 bb = *(const float2*)&b2[2 * t];
    float v0f = a0 + sf.x + bb.x;
    float v1f = a1 + sf.y + bb.y;
    float m = fmaxf(v0f, v1f);
#pragma unroll
    for (int d = 4; d >= 1; d >>= 1) m = fmaxf(m, __shfl_xor(m, d, 8));
    float s = expf(v0f - m) + expf(v1f - m);
#pragma unroll
    for (int d = 4; d >= 1; d >>= 1) s += __shfl_xor(s, d, 8);
    float ls = m + logf(s);
    *(float2*)&out[(size_t)wid * 16 + 2 * t] = make_float2(v0f - ls, v1f - ls);
  }
}

// ---------------------------------------------------------------- launch
extern "C" void kernel_launch(void* const* d_in, const int* in_sizes, int n_in,
                              void* d_out, int out_size, void* d_ws, size_t ws_size,
                              hipStream_t stream) {
  const float* x   = (const float*)d_in[0];
  const int* esrc  = (const int*)d_in[1];
  const int* edst  = (const int*)d_in[2];
  const float* W1  = (const float*)d_in[3];
  // d_in[4] = b1: cancels exactly under batchnorm mean subtraction
  const float* bnw = (const float*)d_in[5];
  const float* bnb = (const float*)d_in[6];
  const float* W2  = (const float*)d_in[7];
  const float* b2  = (const float*)d_in[8];
  float* out = (float*)d_out;

  const int N = in_sizes[0] / 128;  // 100000
  const int E = in_sizes[1];        // 1600000
  const int NB = (N + BNODES - 1) >> BSHIFT;  // 196 buckets

  char* p = (char*)d_ws;
  auto alloc = [&](size_t bytes) {
    char* q = p;
    p += (bytes + 255) & ~(size_t)255;
    return q;
  };
  int* cursor  = (int*)alloc(256 * sizeof(int));
  int* binned  = (int*)alloc((size_t)NB * CAP * sizeof(int));
  int* offs    = (int*)alloc((size_t)(N + 4) * sizeof(int));
  int* csr     = (int*)alloc((size_t)E * sizeof(int));
  float* stats = (float*)alloc((size_t)NSLOT * 128 * sizeof(float));
  float* ab    = (float*)alloc(128 * sizeof(float));
  unsigned short* Wfrag  = (unsigned short*)alloc(1024 * 8 * sizeof(unsigned short));
  unsigned short* W2frag = (unsigned short*)alloc(128 * 8 * sizeof(unsigned short));
  unsigned short* h1 = (unsigned short*)alloc((size_t)(N + 1) * 64 * sizeof(unsigned short));
  unsigned short* h2 = (unsigned short*)alloc((size_t)(N + 1) * 64 * sizeof(unsigned short));
  unsigned short* h3 = (unsigned short*)alloc((size_t)N * 64 * sizeof(unsigned short));
  unsigned short* Yb = (unsigned short*)alloc((size_t)(N + 1) * 16 * sizeof(unsigned short));

  // setup: zero cursor/stats/pad rows + W1/W2 fragment prep (one dispatch)
  k_setup<<<32, 256, 0, stream>>>(cursor, stats, h1 + (size_t)N * 64,
                                  h2 + (size_t)N * 64, Yb + (size_t)N * 16,
                                  W1, Wfrag, W2, W2frag);

  // fused: edge binning + GEMM1 (independent work, co-resident blocks)
  const int nbin = (E + CHUNK - 1) / CHUNK;
  const int ng1 = (N + 63) / 64;
  k_bin_gemm1<<<nbin + ng1, 256, 0, stream>>>(esrc, edst, cursor, binned, E, nbin,
                                              x, Wfrag, h1, N);
  k_build<<<NB, 256, 0, stream>>>(binned, cursor, offs, csr, N, NB, E);

  int hopBlocks = (N * 64 + 255) / 256;  // one wave per node
  k_hop64b<<<hopBlocks, 256, 0, stream>>>(h1, h2, offs, csr, N);
  k_hop64b_stats<<<hopBlocks, 256, 0, stream>>>(h2, h3, offs, csr, stats, N);

  k_finalize_stats<<<1, 64, 0, stream>>>(stats, bnw, bnb, ab, N);

  // GEMM2 (MFMA, fused BN+SELU) before the last hop: hop runs at D=16 fp16
  k_gemm2<<<(N + 63) / 64, 256, 0, stream>>>(h3, ab, W2frag, Yb, N);
  k_hop16<<<hopBlocks, 256, 0, stream>>>(Yb, b2, out, offs, csr, N);
}

// Round 16
// 177.401 us; speedup vs baseline: 1.4712x; 1.0394x over previous
//
#include <hip/hip_runtime.h>
#include <hip/hip_fp16.h>
#include <math.h>

#define SELU_LAMBDA 1.0507009873554805f
#define SELU_ALPHA  1.6732632423543772f

#define BSHIFT 9
#define BNODES 512          // nodes per bucket
#define CAP    10240        // bucket capacity (mean 8192, +22 sigma)
#define CHUNK  4096         // edges per k_bin block
#define NSLOT  64           // stats atomic spreading slots

typedef _Float16 half8 __attribute__((ext_vector_type(8)));
typedef float f32x4 __attribute__((ext_vector_type(4)));

// fp16 helpers
__device__ __forceinline__ unsigned int f2h2(float a, float b) {
  __half2 h = __floats2half2_rn(a, b);
  return *(unsigned int*)&h;
}
__device__ __forceinline__ float2 h22f2(unsigned int u) {
  __half2 h = *(__half2*)&u;
  return __half22float2(h);
}
__device__ __forceinline__ unsigned int hadd2(unsigned int a, unsigned int b) {
  __half2 x = *(__half2*)&a, y = *(__half2*)&b;
  __half2 r = __hadd2(x, y);
  return *(unsigned int*)&r;
}

// ---------------------------------------------------------------- setup: zero cursor/stats/pads + W1/W2 MFMA-fragment prep
__global__ __launch_bounds__(256) void k_setup(int* __restrict__ cursor,
    float* __restrict__ stats, unsigned short* __restrict__ h1pad,
    unsigned short* __restrict__ h2pad, unsigned short* __restrict__ ybpad,
    const float* __restrict__ W1, unsigned short* __restrict__ Wfrag,
    const float* __restrict__ W2, unsigned short* __restrict__ W2frag) {
  int i = blockIdx.x * 256 + threadIdx.x;
  if (i < 256) cursor[i] = 0;
  if (i < NSLOT * 128) stats[i] = 0.f;
  if (i < 64) { h1pad[i] = 0; h2pad[i] = 0; }
  if (i < 16) ybpad[i] = 0;
  if (i < 1024) {  // Wfrag[(ntile*4+kb)*64+lane][8]: W1[k0+j][ntile*16+(lane&15)]
    int lane = i & 63;
    int kb = (i >> 6) & 3;
    int ntile = i >> 8;
    int k0 = kb * 32 + (lane >> 4) * 8;
    int col = ntile * 16 + (lane & 15);
    unsigned short tmp[8];
#pragma unroll
    for (int j = 0; j < 8; ++j) {
      __half h = __float2half_rn(W1[(size_t)(k0 + j) * 64 + col]);
      tmp[j] = *(unsigned short*)&h;
    }
    *(uint4*)&Wfrag[(size_t)i * 8] = *(uint4*)tmp;
  }
  if (i < 128) {   // W2frag[kb*64+lane][8]: W2[k0+j][lane&15]
    int lane = i & 63;
    int kb = i >> 6;
    int k0 = kb * 32 + (lane >> 4) * 8;
    int col = lane & 15;
    unsigned short tmp[8];
#pragma unroll
    for (int j = 0; j < 8; ++j) {
      __half h = __float2half_rn(W2[(size_t)(k0 + j) * 16 + col]);
      tmp[j] = *(unsigned short*)&h;
    }
    *(uint4*)&W2frag[(size_t)i * 8] = *(uint4*)tmp;
  }
}

// ---------------------------------------------------------------- fused: bin edges (blocks < nbin) + MFMA GEMM1 (rest)
__global__ __launch_bounds__(256) void k_bin_gemm1(const int* __restrict__ src,
    const int* __restrict__ dst, int* __restrict__ cursor,
    int* __restrict__ binned, int e, int nbin,
    const float* __restrict__ A, const unsigned short* __restrict__ Wfrag,
    unsigned short* __restrict__ H, int n) {
  if ((int)blockIdx.x < nbin) {
    __shared__ int hist[256];
    __shared__ int gb[256];
    const int tid = threadIdx.x;
    hist[tid] = 0;
    __syncthreads();
    const int base = blockIdx.x * CHUNK;
    int bk[16], rk[16], pk[16];
#pragma unroll
    for (int k = 0; k < 16; ++k) {
      int i = base + k * 256 + tid;
      if (i < e) {
        int d = dst[i];
        int s = src[i];
        int b = d >> BSHIFT;
        bk[k] = b;
        pk[k] = s | ((d & (BNODES - 1)) << 17);
        rk[k] = atomicAdd(&hist[b], 1);
      } else {
        bk[k] = -1;
      }
    }
    __syncthreads();
    int h = hist[tid];
    if (h > 0) gb[tid] = atomicAdd(&cursor[tid], h);
    __syncthreads();
#pragma unroll
    for (int k = 0; k < 16; ++k) {
      if (bk[k] >= 0) binned[bk[k] * CAP + gb[bk[k]] + rk[k]] = pk[k];
    }
    return;
  }
  // ---- gemm1 part
  const int gblk = blockIdx.x - nbin;
  const int lane = threadIdx.x & 63;
  const int wv = threadIdx.x >> 6;
  const int r0 = gblk * 64 + wv * 16;

  const int brow = r0 + (lane & 15);
  const int browc = brow < n ? brow : n - 1;
  const float* xrow = A + (size_t)browc * 128 + (lane >> 4) * 8;

  f32x4 acc[4] = {};
#pragma unroll
  for (int kb = 0; kb < 4; ++kb) {
    float4 p = *(const float4*)(xrow + kb * 32);
    float4 q = *(const float4*)(xrow + kb * 32 + 4);
    half8 xf;
    xf[0] = (_Float16)p.x; xf[1] = (_Float16)p.y;
    xf[2] = (_Float16)p.z; xf[3] = (_Float16)p.w;
    xf[4] = (_Float16)q.x; xf[5] = (_Float16)q.y;
    xf[6] = (_Float16)q.z; xf[7] = (_Float16)q.w;
#pragma unroll
    for (int nt = 0; nt < 4; ++nt) {
      half8 wf = *(const half8*)&Wfrag[(size_t)((nt * 4 + kb) * 64 + lane) * 8];
      acc[nt] = __builtin_amdgcn_mfma_f32_16x16x32_f16(wf, xf, acc[nt], 0, 0, 0);
    }
  }
  const int orow = r0 + (lane & 15);
  if (orow < n) {
#pragma unroll
    for (int nt = 0; nt < 4; ++nt) {
      int col = nt * 16 + (lane >> 4) * 4;
      uint2 o;
      o.x = f2h2(acc[nt][0], acc[nt][1]);
      o.y = f2h2(acc[nt][2], acc[nt][3]);
      *(uint2*)&H[(size_t)orow * 64 + col] = o;
    }
  }
}

// ---------------------------------------------------------------- phase 2: per-bucket CSR build (512 threads)
__global__ __launch_bounds__(512) void k_build(const int* __restrict__ binned,
    const int* __restrict__ cursor, int* __restrict__ offs,
    int* __restrict__ csr, int n, int nb, int etot) {
  __shared__ int sc[2][256];
  __shared__ int deg[BNODES];
  __shared__ int pre[BNODES];
  __shared__ int wsum[8];
  __shared__ int stage[CAP];
  __shared__ int s_cbase;
  const int b = blockIdx.x;
  const int tid = threadIdx.x;

  // replicated inclusive scan of the nb bucket counts (first 256 threads)
  if (tid < 256) sc[0][tid] = (tid < nb) ? cursor[tid] : 0;
  __syncthreads();
  int cur = 0;
  for (int d = 1; d < 256; d <<= 1) {
    if (tid < 256) {
      int t = sc[cur][tid];
      if (tid >= d) t += sc[cur][tid - d];
      sc[cur ^ 1][tid] = t;
    }
    cur ^= 1;
    __syncthreads();
  }
  if (tid == 0) {
    s_cbase = (b == 0) ? 0 : sc[cur][b - 1];
    if (b == 0) offs[n] = etot;
  }
  deg[tid] = 0;
  __syncthreads();
  const int cbase = s_cbase;
  const int cnt = sc[cur][b] - cbase;

  const int nodeBase = b << BSHIFT;
  const int* gsrc = binned + b * CAP;

  for (int i = tid; i < cnt; i += 512) atomicAdd(&deg[gsrc[i] >> 17], 1);
  __syncthreads();

  // exclusive scan of deg[512]: 1 element/thread (8 waves)
  const int lane = tid & 63, w = tid >> 6;
  int a0 = deg[tid];
  int s = a0;
#pragma unroll
  for (int d = 1; d < 64; d <<= 1) {
    int t = __shfl_up(s, d, 64);
    if (lane >= d) s += t;
  }
  if (lane == 63) wsum[w] = s;
  __syncthreads();
  if (tid == 0) {
    int acc = 0;
#pragma unroll
    for (int j = 0; j < 8; ++j) { int t = wsum[j]; wsum[j] = acc; acc += t; }
  }
  __syncthreads();
  pre[tid] = wsum[w] + s - a0;
  deg[tid] = 0;   // reset for use as cursor
  __syncthreads();

  const int nNodes = min(BNODES, n - nodeBase);
  for (int i = tid; i < nNodes; i += 512) offs[nodeBase + i] = cbase + pre[i];

  for (int i = tid; i < cnt; i += 512) {
    int v = gsrc[i];
    int dl = v >> 17;
    int p = pre[dl] + atomicAdd(&deg[dl], 1);
    stage[p] = v & 0x1FFFF;
  }
  __syncthreads();
  for (int i = tid; i < cnt; i += 512) csr[cbase + i] = stage[i];
}

// ---------------------------------------------------------------- hop at D=64 (fp16 in/out)
// one wave per node; 4 sub-groups of 16 lanes; lane loads 4 dims (8B).
// All 32 edge indices preloaded (pad = zero row n); tail for deg > 32.
__device__ __forceinline__ void hop64_gather32(const unsigned short* __restrict__ hin,
    const int* __restrict__ csr, int beg, int end, int sub, int t, int npad,
    unsigned int& a01, unsigned int& a23) {
  a01 = 0u; a23 = 0u;
  int idx[8];
#pragma unroll
  for (int k = 0; k < 8; ++k) {
    int a = beg + k * 4 + sub;
    idx[k] = (a < end) ? csr[a] : npad;
  }
  uint2 v[8];
#pragma unroll
  for (int k = 0; k < 8; ++k)
    v[k] = *(const uint2*)&hin[(size_t)idx[k] * 64 + 4 * t];
#pragma unroll
  for (int k = 0; k < 8; ++k) {
    a01 = hadd2(a01, v[k].x);
    a23 = hadd2(a23, v[k].y);
  }
  for (int eb = beg + 32; eb < end; eb += 16) {   // rare tail (P ~ 1e-4)
    int jx[4];
#pragma unroll
    for (int k = 0; k < 4; ++k) {
      int a = eb + k * 4 + sub;
      jx[k] = (a < end) ? csr[a] : npad;
    }
    uint2 w[4];
#pragma unroll
    for (int k = 0; k < 4; ++k)
      w[k] = *(const uint2*)&hin[(size_t)jx[k] * 64 + 4 * t];
#pragma unroll
    for (int k = 0; k < 4; ++k) {
      a01 = hadd2(a01, w[k].x);
      a23 = hadd2(a23, w[k].y);
    }
  }
}

__global__ __launch_bounds__(256) void k_hop64b(const unsigned short* __restrict__ hin,
    unsigned short* __restrict__ hout, const int* __restrict__ offs,
    const int* __restrict__ csr, int n) {
  int wid = (blockIdx.x * 256 + threadIdx.x) >> 6;
  if (wid >= n) return;
  int lane = threadIdx.x & 63;
  int sub = lane >> 4, t = lane & 15;
  int beg = offs[wid], end = offs[wid + 1];
  unsigned int a01, a23;
  hop64_gather32(hin, csr, beg, end, sub, t, n, a01, a23);
  a01 = hadd2(a01, (unsigned int)__shfl_down((int)a01, 32, 64));
  a23 = hadd2(a23, (unsigned int)__shfl_down((int)a23, 32, 64));
  a01 = hadd2(a01, (unsigned int)__shfl_down((int)a01, 16, 64));
  a23 = hadd2(a23, (unsigned int)__shfl_down((int)a23, 16, 64));
  if (sub == 0) {
    uint2 sv = *(const uint2*)&hin[(size_t)wid * 64 + 4 * t];
    uint2 o;
    o.x = hadd2(a01, sv.x);
    o.y = hadd2(a23, sv.y);
    *(uint2*)&hout[(size_t)wid * 64 + 4 * t] = o;
  }
}

// hop2: fp16 in/out, fused per-column (sum, sumsq) batch stats (fp32 epilogue)
__global__ __launch_bounds__(256) void k_hop64b_stats(const unsigned short* __restrict__ hin,
    unsigned short* __restrict__ hout, const int* __restrict__ offs,
    const int* __restrict__ csr, float* __restrict__ stats, int n) {
  int wid = (blockIdx.x * 256 + threadIdx.x) >> 6;
  int lane = threadIdx.x & 63;
  int sub = lane >> 4, t = lane & 15;
  float f0 = 0.f, f1 = 0.f, f2 = 0.f, f3 = 0.f;
  if (wid < n) {
    int beg = offs[wid], end = offs[wid + 1];
    unsigned int a01, a23;
    hop64_gather32(hin, csr, beg, end, sub, t, n, a01, a23);
    a01 = hadd2(a01, (unsigned int)__shfl_down((int)a01, 32, 64));
    a23 = hadd2(a23, (unsigned int)__shfl_down((int)a23, 32, 64));
    a01 = hadd2(a01, (unsigned int)__shfl_down((int)a01, 16, 64));
    a23 = hadd2(a23, (unsigned int)__shfl_down((int)a23, 16, 64));
    if (sub == 0) {
      uint2 sv = *(const uint2*)&hin[(size_t)wid * 64 + 4 * t];
      uint2 o;
      o.x = hadd2(a01, sv.x);
      o.y = hadd2(a23, sv.y);
      *(uint2*)&hout[(size_t)wid * 64 + 4 * t] = o;
      float2 p01 = h22f2(o.x), p23 = h22f2(o.y);
      f0 = p01.x; f1 = p01.y; f2 = p23.x; f3 = p23.y;
    }
  }
  __shared__ float l1[4][64];
  __shared__ float l2[4][64];
  const int w = threadIdx.x >> 6;
  if (sub == 0) {
    *(float4*)&l1[w][4 * t] = make_float4(f0, f1, f2, f3);
    *(float4*)&l2[w][4 * t] = make_float4(f0 * f0, f1 * f1, f2 * f2, f3 * f3);
  }
  __syncthreads();
  if (threadIdx.x < 64) {
    float t1 = l1[0][threadIdx.x] + l1[1][threadIdx.x] + l1[2][threadIdx.x] + l1[3][threadIdx.x];
    float t2 = l2[0][threadIdx.x] + l2[1][threadIdx.x] + l2[2][threadIdx.x] + l2[3][threadIdx.x];
    float* slot = stats + (size_t)(blockIdx.x & (NSLOT - 1)) * 128;
    atomicAdd(&slot[threadIdx.x], t1);
    atomicAdd(&slot[64 + threadIdx.x], t2);
  }
}

// ---------------------------------------------------------------- GEMM2 via MFMA with folded stats-finalize
// per block: reduce NSLOT stat copies -> ab[128] in LDS; then
// wave = 16 rows; B-frag = selu(bn(h3-row)) 8 dims/lane; A-frag = W2frag.
__global__ __launch_bounds__(256) void k_gemm2(const unsigned short* __restrict__ A,
    const float* __restrict__ stats, const float* __restrict__ bn_w,
    const float* __restrict__ bn_b, const unsigned short* __restrict__ W2frag,
    unsigned short* __restrict__ Y, int n) {
  __shared__ float ab[128];
  if (threadIdx.x < 64) {
    int f = threadIdx.x;
    float s1 = 0.f, s2 = 0.f;
#pragma unroll 4
    for (int j = 0; j < NSLOT; ++j) {
      s1 += stats[(size_t)j * 128 + f];
      s2 += stats[(size_t)j * 128 + 64 + f];
    }
    float inv_n = 1.0f / (float)n;
    float mu = s1 * inv_n;
    float var = s2 * inv_n - mu * mu;
    float s = bn_w[f] * rsqrtf(var + 1e-5f);
    ab[f] = s;
    ab[64 + f] = bn_b[f] - mu * s;
  }
  __syncthreads();

  const int lane = threadIdx.x & 63;
  const int wv = threadIdx.x >> 6;
  const int r0 = blockIdx.x * 64 + wv * 16;
  const int brow = r0 + (lane & 15);
  const int browc = brow < n ? brow : n - 1;
  const int kbase = (lane >> 4) * 8;

  f32x4 acc = {};
#pragma unroll
  for (int kb = 0; kb < 2; ++kb) {
    int k0 = kb * 32 + kbase;
    uint4 a = *(const uint4*)&A[(size_t)browc * 64 + k0];
    unsigned int pk[4] = {a.x, a.y, a.z, a.w};
    half8 yf;
#pragma unroll
    for (int q = 0; q < 4; ++q) {
      float2 f2v = h22f2(pk[q]);
      float s0 = ab[k0 + 2 * q], sh0 = ab[64 + k0 + 2 * q];
      float s1 = ab[k0 + 2 * q + 1], sh1 = ab[64 + k0 + 2 * q + 1];
      float y0 = s0 * f2v.x + sh0;
      float y1 = s1 * f2v.y + sh1;
      y0 = y0 > 0.f ? SELU_LAMBDA * y0 : SELU_LAMBDA * SELU_ALPHA * expm1f(y0);
      y1 = y1 > 0.f ? SELU_LAMBDA * y1 : SELU_LAMBDA * SELU_ALPHA * expm1f(y1);
      yf[2 * q] = (_Float16)y0;
      yf[2 * q + 1] = (_Float16)y1;
    }
    half8 wf = *(const half8*)&W2frag[(size_t)(kb * 64 + lane) * 8];
    acc = __builtin_amdgcn_mfma_f32_16x16x32_f16(wf, yf, acc, 0, 0, 0);
  }
  const int orow = r0 + (lane & 15);
  if (orow < n) {
    uint2 o;
    o.x = f2h2(acc[0], acc[1]);
    o.y = f2h2(acc[2], acc[3]);
    *(uint2*)&Y[(size_t)orow * 16 + (lane >> 4) * 4] = o;
  }
}

// ---------------------------------------------------------------- hop at D=16 (fp16) + b2 + log_softmax
// one wave per node; 16 subgroups x 4 lanes; lane loads uint2 (4 dims)
// -> 16 edges per gather instruction; 32 edges preloaded; pad = zero row n.
__global__ __launch_bounds__(256) void k_hop16(const unsigned short* __restrict__ Y,
    const float* __restrict__ b2, float* __restrict__ out,
    const int* __restrict__ offs, const int* __restrict__ csr, int n) {
  int wid = (blockIdx.x * 256 + threadIdx.x) >> 6;
  if (wid >= n) return;
  int lane = threadIdx.x & 63;
  int sub = lane >> 2, t = lane & 3;   // lane covers dims 4t..4t+3
  int beg = offs[wid], end = offs[wid + 1];
  int i0, i1;
  {
    int a0i = beg + sub, a1i = beg + 16 + sub;
    i0 = (a0i < end) ? csr[a0i] : n;
    i1 = (a1i < end) ? csr[a1i] : n;
  }
  uint2 v0 = *(const uint2*)&Y[(size_t)i0 * 16 + 4 * t];
  uint2 v1 = *(const uint2*)&Y[(size_t)i1 * 16 + 4 * t];
  unsigned int a01 = hadd2(v0.x, v1.x);
  unsigned int a23 = hadd2(v0.y, v1.y);
  for (int eb = beg + 32; eb < end; eb += 16) {   // rare tail
    int a = eb + sub;
    int idx = (a < end) ? csr[a] : n;
    uint2 w = *(const uint2*)&Y[(size_t)idx * 16 + 4 * t];
    a01 = hadd2(a01, w.x);
    a23 = hadd2(a23, w.y);
  }
  a01 = hadd2(a01, (unsigned int)__shfl_down((int)a01, 32, 64));
  a23 = hadd2(a23, (unsigned int)__shfl_down((int)a23, 32, 64));
  a01 = hadd2(a01, (unsigned int)__shfl_down((int)a01, 16, 64));
  a23 = hadd2(a23, (unsigned int)__shfl_down((int)a23, 16, 64));
  a01 = hadd2(a01, (unsigned int)__shfl_down((int)a01, 8, 64));
  a23 = hadd2(a23, (unsigned int)__shfl_down((int)a23, 8, 64));
  a01 = hadd2(a01, (unsigned int)__shfl_down((int)a01, 4, 64));
  a23 = hadd2(a23, (unsigned int)__shfl_down((int)a23, 4, 64));
  if (sub == 0) {
    uint2 sv = *(const uint2*)&Y[(size_t)wid * 16 + 4 * t];
    float2 s01 = h22f2(sv.x), s23 = h22f2(sv.y);
    float2 p01 = h22f2(a01), p23 = h22f2(a23);
    float4 bb = *(const float4*)&b2[4 * t];
    float v0f = p01.x + s01.x + bb.x;
    float v1f = p01.y + s01.y + bb.y;
    float v2f = p23.x + s23.x + bb.z;
    float v3f = p23.y + s23.y + bb.w;
    float m = fmaxf(fmaxf(v0f, v1f), fmaxf(v2f, v3f));
    m = fmaxf(m, __shfl_xor(m, 1, 4));
    m = fmaxf(m, __shfl_xor(m, 2, 4));
    float s = expf(v0f - m) + expf(v1f - m) + expf(v2f - m) + expf(v3f - m);
    s += __shfl_xor(s, 1, 4);
    s += __shfl_xor(s, 2, 4);
    float ls = m + logf(s);
    *(float4*)&out[(size_t)wid * 16 + 4 * t] =
        make_float4(v0f - ls, v1f - ls, v2f - ls, v3f - ls);
  }
}

// ---------------------------------------------------------------- launch
extern "C" void kernel_launch(void* const* d_in, const int* in_sizes, int n_in,
                              void* d_out, int out_size, void* d_ws, size_t ws_size,
                              hipStream_t stream) {
  const float* x   = (const float*)d_in[0];
  const int* esrc  = (const int*)d_in[1];
  const int* edst  = (const int*)d_in[2];
  const float* W1  = (const float*)d_in[3];
  // d_in[4] = b1: cancels exactly under batchnorm mean subtraction
  const float* bnw = (const float*)d_in[5];
  const float* bnb = (const float*)d_in[6];
  const float* W2  = (const float*)d_in[7];
  const float* b2  = (const float*)d_in[8];
  float* out = (float*)d_out;

  const int N = in_sizes[0] / 128;  // 100000
  const int E = in_sizes[1];        // 1600000
  const int NB = (N + BNODES - 1) >> BSHIFT;  // 196 buckets

  char* p = (char*)d_ws;
  auto alloc = [&](size_t bytes) {
    char* q = p;
    p += (bytes + 255) & ~(size_t)255;
    return q;
  };
  int* cursor  = (int*)alloc(256 * sizeof(int));
  int* binned  = (int*)alloc((size_t)NB * CAP * sizeof(int));
  int* offs    = (int*)alloc((size_t)(N + 4) * sizeof(int));
  int* csr     = (int*)alloc((size_t)E * sizeof(int));
  float* stats = (float*)alloc((size_t)NSLOT * 128 * sizeof(float));
  unsigned short* Wfrag  = (unsigned short*)alloc(1024 * 8 * sizeof(unsigned short));
  unsigned short* W2frag = (unsigned short*)alloc(128 * 8 * sizeof(unsigned short));
  unsigned short* h1 = (unsigned short*)alloc((size_t)(N + 1) * 64 * sizeof(unsigned short));
  unsigned short* h2 = (unsigned short*)alloc((size_t)(N + 1) * 64 * sizeof(unsigned short));
  unsigned short* h3 = (unsigned short*)alloc((size_t)N * 64 * sizeof(unsigned short));
  unsigned short* Yb = (unsigned short*)alloc((size_t)(N + 1) * 16 * sizeof(unsigned short));

  // setup: zero cursor/stats/pad rows + W1/W2 fragment prep (one dispatch)
  k_setup<<<32, 256, 0, stream>>>(cursor, stats, h1 + (size_t)N * 64,
                                  h2 + (size_t)N * 64, Yb + (size_t)N * 16,
                                  W1, Wfrag, W2, W2frag);

  // fused: edge binning + GEMM1 (independent work, co-resident blocks)
  const int nbin = (E + CHUNK - 1) / CHUNK;
  const int ng1 = (N + 63) / 64;
  k_bin_gemm1<<<nbin + ng1, 256, 0, stream>>>(esrc, edst, cursor, binned, E, nbin,
                                              x, Wfrag, h1, N);
  k_build<<<NB, 512, 0, stream>>>(binned, cursor, offs, csr, N, NB, E);

  int hopBlocks = (N * 64 + 255) / 256;  // one wave per node
  k_hop64b<<<hopBlocks, 256, 0, stream>>>(h1, h2, offs, csr, N);
  k_hop64b_stats<<<hopBlocks, 256, 0, stream>>>(h2, h3, offs, csr, stats, N);

  // GEMM2 (MFMA, folded stats-finalize + BN + SELU) then final hop at D=16
  k_gemm2<<<(N + 63) / 64, 256, 0, stream>>>(h3, stats, bnw, bnb, W2frag, Yb, N);
  k_hop16<<<hopBlocks, 256, 0, stream>>>(Yb, b2, out, offs, csr, N);
}

// Round 17
// 172.436 us; speedup vs baseline: 1.5135x; 1.0288x over previous
//
#include <hip/hip_runtime.h>
#include <hip/hip_fp16.h>
#include <math.h>

#define SELU_LAMBDA 1.0507009873554805f
#define SELU_ALPHA  1.6732632423543772f

#define BSHIFT 9
#define BNODES 512          // nodes per bucket
#define CAP    10240        // bucket capacity (mean 8192, +22 sigma)
#define CHUNK  4096         // edges per k_bin block
#define NSLOT  64           // stats atomic spreading slots
#define HOPBLKS 2048        // persistent hop blocks (8/CU -> 32 waves/CU)

typedef _Float16 half8 __attribute__((ext_vector_type(8)));
typedef float f32x4 __attribute__((ext_vector_type(4)));

// fp16 helpers
__device__ __forceinline__ unsigned int f2h2(float a, float b) {
  __half2 h = __floats2half2_rn(a, b);
  return *(unsigned int*)&h;
}
__device__ __forceinline__ float2 h22f2(unsigned int u) {
  __half2 h = *(__half2*)&u;
  return __half22float2(h);
}
__device__ __forceinline__ unsigned int hadd2(unsigned int a, unsigned int b) {
  __half2 x = *(__half2*)&a, y = *(__half2*)&b;
  __half2 r = __hadd2(x, y);
  return *(unsigned int*)&r;
}

// ---------------------------------------------------------------- setup: zero cursor/stats/pads + W1/W2 MFMA-fragment prep
__global__ __launch_bounds__(256) void k_setup(int* __restrict__ cursor,
    float* __restrict__ stats, unsigned short* __restrict__ h1pad,
    unsigned short* __restrict__ h2pad, unsigned short* __restrict__ ybpad,
    const float* __restrict__ W1, unsigned short* __restrict__ Wfrag,
    const float* __restrict__ W2, unsigned short* __restrict__ W2frag) {
  int i = blockIdx.x * 256 + threadIdx.x;
  if (i < 256) cursor[i] = 0;
  if (i < NSLOT * 128) stats[i] = 0.f;
  if (i < 64) { h1pad[i] = 0; h2pad[i] = 0; }
  if (i < 16) ybpad[i] = 0;
  if (i < 1024) {  // Wfrag[(ntile*4+kb)*64+lane][8]: W1[k0+j][ntile*16+(lane&15)]
    int lane = i & 63;
    int kb = (i >> 6) & 3;
    int ntile = i >> 8;
    int k0 = kb * 32 + (lane >> 4) * 8;
    int col = ntile * 16 + (lane & 15);
    unsigned short tmp[8];
#pragma unroll
    for (int j = 0; j < 8; ++j) {
      __half h = __float2half_rn(W1[(size_t)(k0 + j) * 64 + col]);
      tmp[j] = *(unsigned short*)&h;
    }
    *(uint4*)&Wfrag[(size_t)i * 8] = *(uint4*)tmp;
  }
  if (i < 128) {   // W2frag[kb*64+lane][8]: W2[k0+j][lane&15]
    int lane = i & 63;
    int kb = i >> 6;
    int k0 = kb * 32 + (lane >> 4) * 8;
    int col = lane & 15;
    unsigned short tmp[8];
#pragma unroll
    for (int j = 0; j < 8; ++j) {
      __half h = __float2half_rn(W2[(size_t)(k0 + j) * 16 + col]);
      tmp[j] = *(unsigned short*)&h;
    }
    *(uint4*)&W2frag[(size_t)i * 8] = *(uint4*)tmp;
  }
}

// ---------------------------------------------------------------- fused: bin edges (blocks < nbin) + MFMA GEMM1 (rest)
__global__ __launch_bounds__(256) void k_bin_gemm1(const int* __restrict__ src,
    const int* __restrict__ dst, int* __restrict__ cursor,
    int* __restrict__ binned, int e, int nbin,
    const float* __restrict__ A, const unsigned short* __restrict__ Wfrag,
    unsigned short* __restrict__ H, int n) {
  if ((int)blockIdx.x < nbin) {
    __shared__ int hist[256];
    __shared__ int gb[256];
    const int tid = threadIdx.x;
    hist[tid] = 0;
    __syncthreads();
    const int base = blockIdx.x * CHUNK;
    int bk[16], rk[16], pk[16];
#pragma unroll
    for (int k = 0; k < 16; ++k) {
      int i = base + k * 256 + tid;
      if (i < e) {
        int d = dst[i];
        int s = src[i];
        int b = d >> BSHIFT;
        bk[k] = b;
        pk[k] = s | ((d & (BNODES - 1)) << 17);
        rk[k] = atomicAdd(&hist[b], 1);
      } else {
        bk[k] = -1;
      }
    }
    __syncthreads();
    int h = hist[tid];
    if (h > 0) gb[tid] = atomicAdd(&cursor[tid], h);
    __syncthreads();
#pragma unroll
    for (int k = 0; k < 16; ++k) {
      if (bk[k] >= 0) binned[bk[k] * CAP + gb[bk[k]] + rk[k]] = pk[k];
    }
    return;
  }
  // ---- gemm1 part
  const int gblk = blockIdx.x - nbin;
  const int lane = threadIdx.x & 63;
  const int wv = threadIdx.x >> 6;
  const int r0 = gblk * 64 + wv * 16;

  const int brow = r0 + (lane & 15);
  const int browc = brow < n ? brow : n - 1;
  const float* xrow = A + (size_t)browc * 128 + (lane >> 4) * 8;

  f32x4 acc[4] = {};
#pragma unroll
  for (int kb = 0; kb < 4; ++kb) {
    float4 p = *(const float4*)(xrow + kb * 32);
    float4 q = *(const float4*)(xrow + kb * 32 + 4);
    half8 xf;
    xf[0] = (_Float16)p.x; xf[1] = (_Float16)p.y;
    xf[2] = (_Float16)p.z; xf[3] = (_Float16)p.w;
    xf[4] = (_Float16)q.x; xf[5] = (_Float16)q.y;
    xf[6] = (_Float16)q.z; xf[7] = (_Float16)q.w;
#pragma unroll
    for (int nt = 0; nt < 4; ++nt) {
      half8 wf = *(const half8*)&Wfrag[(size_t)((nt * 4 + kb) * 64 + lane) * 8];
      acc[nt] = __builtin_amdgcn_mfma_f32_16x16x32_f16(wf, xf, acc[nt], 0, 0, 0);
    }
  }
  const int orow = r0 + (lane & 15);
  if (orow < n) {
#pragma unroll
    for (int nt = 0; nt < 4; ++nt) {
      int col = nt * 16 + (lane >> 4) * 4;
      uint2 o;
      o.x = f2h2(acc[nt][0], acc[nt][1]);
      o.y = f2h2(acc[nt][2], acc[nt][3]);
      *(uint2*)&H[(size_t)orow * 64 + col] = o;
    }
  }
}

// ---------------------------------------------------------------- phase 2: per-bucket CSR build (512 threads)
__global__ __launch_bounds__(512) void k_build(const int* __restrict__ binned,
    const int* __restrict__ cursor, int* __restrict__ offs,
    int* __restrict__ csr, int n, int nb, int etot) {
  __shared__ int sc[2][256];
  __shared__ int deg[BNODES];
  __shared__ int pre[BNODES];
  __shared__ int wsum[8];
  __shared__ int stage[CAP];
  __shared__ int s_cbase;
  const int b = blockIdx.x;
  const int tid = threadIdx.x;

  // replicated inclusive scan of the nb bucket counts (first 256 threads)
  if (tid < 256) sc[0][tid] = (tid < nb) ? cursor[tid] : 0;
  __syncthreads();
  int cur = 0;
  for (int d = 1; d < 256; d <<= 1) {
    if (tid < 256) {
      int t = sc[cur][tid];
      if (tid >= d) t += sc[cur][tid - d];
      sc[cur ^ 1][tid] = t;
    }
    cur ^= 1;
    __syncthreads();
  }
  if (tid == 0) {
    s_cbase = (b == 0) ? 0 : sc[cur][b - 1];
    if (b == 0) offs[n] = etot;
  }
  deg[tid] = 0;
  __syncthreads();
  const int cbase = s_cbase;
  const int cnt = sc[cur][b] - cbase;

  const int nodeBase = b << BSHIFT;
  const int* gsrc = binned + b * CAP;

  for (int i = tid; i < cnt; i += 512) atomicAdd(&deg[gsrc[i] >> 17], 1);
  __syncthreads();

  // exclusive scan of deg[512]: 1 element/thread (8 waves)
  const int lane = tid & 63, w = tid >> 6;
  int a0 = deg[tid];
  int s = a0;
#pragma unroll
  for (int d = 1; d < 64; d <<= 1) {
    int t = __shfl_up(s, d, 64);
    if (lane >= d) s += t;
  }
  if (lane == 63) wsum[w] = s;
  __syncthreads();
  if (tid == 0) {
    int acc = 0;
#pragma unroll
    for (int j = 0; j < 8; ++j) { int t = wsum[j]; wsum[j] = acc; acc += t; }
  }
  __syncthreads();
  pre[tid] = wsum[w] + s - a0;
  deg[tid] = 0;   // reset for use as cursor
  __syncthreads();

  const int nNodes = min(BNODES, n - nodeBase);
  for (int i = tid; i < nNodes; i += 512) offs[nodeBase + i] = cbase + pre[i];

  for (int i = tid; i < cnt; i += 512) {
    int v = gsrc[i];
    int dl = v >> 17;
    int p = pre[dl] + atomicAdd(&deg[dl], 1);
    stage[p] = v & 0x1FFFF;
  }
  __syncthreads();
  for (int i = tid; i < cnt; i += 512) csr[cbase + i] = stage[i];
}

// ---------------------------------------------------------------- hop at D=64 (fp16 in/out), persistent grid-stride
// wave = one node per iteration; 4 sub-groups of 16 lanes; lane loads 4 dims (8B).
// All 32 edge indices preloaded (pad = zero row n); tail for deg > 32.
__device__ __forceinline__ void hop64_gather32(const unsigned short* __restrict__ hin,
    const int* __restrict__ csr, int beg, int end, int sub, int t, int npad,
    unsigned int& a01, unsigned int& a23) {
  a01 = 0u; a23 = 0u;
  int idx[8];
#pragma unroll
  for (int k = 0; k < 8; ++k) {
    int a = beg + k * 4 + sub;
    idx[k] = (a < end) ? csr[a] : npad;
  }
  uint2 v[8];
#pragma unroll
  for (int k = 0; k < 8; ++k)
    v[k] = *(const uint2*)&hin[(size_t)idx[k] * 64 + 4 * t];
#pragma unroll
  for (int k = 0; k < 8; ++k) {
    a01 = hadd2(a01, v[k].x);
    a23 = hadd2(a23, v[k].y);
  }
  for (int eb = beg + 32; eb < end; eb += 16) {   // rare tail (P ~ 1e-4)
    int jx[4];
#pragma unroll
    for (int k = 0; k < 4; ++k) {
      int a = eb + k * 4 + sub;
      jx[k] = (a < end) ? csr[a] : npad;
    }
    uint2 w[4];
#pragma unroll
    for (int k = 0; k < 4; ++k)
      w[k] = *(const uint2*)&hin[(size_t)jx[k] * 64 + 4 * t];
#pragma unroll
    for (int k = 0; k < 4; ++k) {
      a01 = hadd2(a01, w[k].x);
      a23 = hadd2(a23, w[k].y);
    }
  }
}

__global__ __launch_bounds__(256) void k_hop64b(const unsigned short* __restrict__ hin,
    unsigned short* __restrict__ hout, const int* __restrict__ offs,
    const int* __restrict__ csr, int n, int nwaves) {
  const int lane = threadIdx.x & 63;
  const int sub = lane >> 4, t = lane & 15;
  for (int wid = blockIdx.x * 4 + (threadIdx.x >> 6); wid < n; wid += nwaves) {
    int beg = offs[wid], end = offs[wid + 1];
    unsigned int a01, a23;
    hop64_gather32(hin, csr, beg, end, sub, t, n, a01, a23);
    a01 = hadd2(a01, (unsigned int)__shfl_down((int)a01, 32, 64));
    a23 = hadd2(a23, (unsigned int)__shfl_down((int)a23, 32, 64));
    a01 = hadd2(a01, (unsigned int)__shfl_down((int)a01, 16, 64));
    a23 = hadd2(a23, (unsigned int)__shfl_down((int)a23, 16, 64));
    if (sub == 0) {
      uint2 sv = *(const uint2*)&hin[(size_t)wid * 64 + 4 * t];
      uint2 o;
      o.x = hadd2(a01, sv.x);
      o.y = hadd2(a23, sv.y);
      *(uint2*)&hout[(size_t)wid * 64 + 4 * t] = o;
    }
  }
}

// hop2: persistent grid-stride; stats accumulated in registers, one epilogue/block
__global__ __launch_bounds__(256) void k_hop64b_stats(const unsigned short* __restrict__ hin,
    unsigned short* __restrict__ hout, const int* __restrict__ offs,
    const int* __restrict__ csr, float* __restrict__ stats, int n, int nwaves) {
  const int lane = threadIdx.x & 63;
  const int sub = lane >> 4, t = lane & 15;
  float g1[4] = {}, g2[4] = {};
  for (int wid = blockIdx.x * 4 + (threadIdx.x >> 6); wid < n; wid += nwaves) {
    int beg = offs[wid], end = offs[wid + 1];
    unsigned int a01, a23;
    hop64_gather32(hin, csr, beg, end, sub, t, n, a01, a23);
    a01 = hadd2(a01, (unsigned int)__shfl_down((int)a01, 32, 64));
    a23 = hadd2(a23, (unsigned int)__shfl_down((int)a23, 32, 64));
    a01 = hadd2(a01, (unsigned int)__shfl_down((int)a01, 16, 64));
    a23 = hadd2(a23, (unsigned int)__shfl_down((int)a23, 16, 64));
    if (sub == 0) {
      uint2 sv = *(const uint2*)&hin[(size_t)wid * 64 + 4 * t];
      uint2 o;
      o.x = hadd2(a01, sv.x);
      o.y = hadd2(a23, sv.y);
      *(uint2*)&hout[(size_t)wid * 64 + 4 * t] = o;
      float2 p01 = h22f2(o.x), p23 = h22f2(o.y);
      g1[0] += p01.x; g2[0] += p01.x * p01.x;
      g1[1] += p01.y; g2[1] += p01.y * p01.y;
      g1[2] += p23.x; g2[2] += p23.x * p23.x;
      g1[3] += p23.y; g2[3] += p23.y * p23.y;
    }
  }
  __shared__ float l1[4][64];
  __shared__ float l2[4][64];
  const int w = threadIdx.x >> 6;
  if (sub == 0) {
    *(float4*)&l1[w][4 * t] = make_float4(g1[0], g1[1], g1[2], g1[3]);
    *(float4*)&l2[w][4 * t] = make_float4(g2[0], g2[1], g2[2], g2[3]);
  }
  __syncthreads();
  if (threadIdx.x < 64) {
    float t1 = l1[0][threadIdx.x] + l1[1][threadIdx.x] + l1[2][threadIdx.x] + l1[3][threadIdx.x];
    float t2 = l2[0][threadIdx.x] + l2[1][threadIdx.x] + l2[2][threadIdx.x] + l2[3][threadIdx.x];
    float* slot = stats + (size_t)(blockIdx.x & (NSLOT - 1)) * 128;
    atomicAdd(&slot[threadIdx.x], t1);
    atomicAdd(&slot[64 + threadIdx.x], t2);
  }
}

// ---------------------------------------------------------------- GEMM2 via MFMA with folded stats-finalize
__global__ __launch_bounds__(256) void k_gemm2(const unsigned short* __restrict__ A,
    const float* __restrict__ stats, const float* __restrict__ bn_w,
    const float* __restrict__ bn_b, const unsigned short* __restrict__ W2frag,
    unsigned short* __restrict__ Y, int n) {
  __shared__ float ab[128];
  if (threadIdx.x < 64) {
    int f = threadIdx.x;
    float s1 = 0.f, s2 = 0.f;
#pragma unroll 4
    for (int j = 0; j < NSLOT; ++j) {
      s1 += stats[(size_t)j * 128 + f];
      s2 += stats[(size_t)j * 128 + 64 + f];
    }
    float inv_n = 1.0f / (float)n;
    float mu = s1 * inv_n;
    float var = s2 * inv_n - mu * mu;
    float s = bn_w[f] * rsqrtf(var + 1e-5f);
    ab[f] = s;
    ab[64 + f] = bn_b[f] - mu * s;
  }
  __syncthreads();

  const int lane = threadIdx.x & 63;
  const int wv = threadIdx.x >> 6;
  const int r0 = blockIdx.x * 64 + wv * 16;
  const int brow = r0 + (lane & 15);
  const int browc = brow < n ? brow : n - 1;
  const int kbase = (lane >> 4) * 8;

  f32x4 acc = {};
#pragma unroll
  for (int kb = 0; kb < 2; ++kb) {
    int k0 = kb * 32 + kbase;
    uint4 a = *(const uint4*)&A[(size_t)browc * 64 + k0];
    unsigned int pk[4] = {a.x, a.y, a.z, a.w};
    half8 yf;
#pragma unroll
    for (int q = 0; q < 4; ++q) {
      float2 f2v = h22f2(pk[q]);
      float s0 = ab[k0 + 2 * q], sh0 = ab[64 + k0 + 2 * q];
      float s1 = ab[k0 + 2 * q + 1], sh1 = ab[64 + k0 + 2 * q + 1];
      float y0 = s0 * f2v.x + sh0;
      float y1 = s1 * f2v.y + sh1;
      y0 = y0 > 0.f ? SELU_LAMBDA * y0 : SELU_LAMBDA * SELU_ALPHA * expm1f(y0);
      y1 = y1 > 0.f ? SELU_LAMBDA * y1 : SELU_LAMBDA * SELU_ALPHA * expm1f(y1);
      yf[2 * q] = (_Float16)y0;
      yf[2 * q + 1] = (_Float16)y1;
    }
    half8 wf = *(const half8*)&W2frag[(size_t)(kb * 64 + lane) * 8];
    acc = __builtin_amdgcn_mfma_f32_16x16x32_f16(wf, yf, acc, 0, 0, 0);
  }
  const int orow = r0 + (lane & 15);
  if (orow < n) {
    uint2 o;
    o.x = f2h2(acc[0], acc[1]);
    o.y = f2h2(acc[2], acc[3]);
    *(uint2*)&Y[(size_t)orow * 16 + (lane >> 4) * 4] = o;
  }
}

// ---------------------------------------------------------------- hop at D=16 (fp16) + b2 + log_softmax, persistent grid-stride
// wave = one node per iteration; 16 subgroups x 4 lanes; lane loads uint2 (4 dims)
__global__ __launch_bounds__(256) void k_hop16(const unsigned short* __restrict__ Y,
    const float* __restrict__ b2, float* __restrict__ out,
    const int* __restrict__ offs, const int* __restrict__ csr, int n, int nwaves) {
  const int lane = threadIdx.x & 63;
  const int sub = lane >> 2, t = lane & 3;   // lane covers dims 4t..4t+3
  for (int wid = blockIdx.x * 4 + (threadIdx.x >> 6); wid < n; wid += nwaves) {
    int beg = offs[wid], end = offs[wid + 1];
    int i0, i1;
    {
      int a0i = beg + sub, a1i = beg + 16 + sub;
      i0 = (a0i < end) ? csr[a0i] : n;
      i1 = (a1i < end) ? csr[a1i] : n;
    }
    uint2 v0 = *(const uint2*)&Y[(size_t)i0 * 16 + 4 * t];
    uint2 v1 = *(const uint2*)&Y[(size_t)i1 * 16 + 4 * t];
    unsigned int a01 = hadd2(v0.x, v1.x);
    unsigned int a23 = hadd2(v0.y, v1.y);
    for (int eb = beg + 32; eb < end; eb += 16) {   // rare tail
      int a = eb + sub;
      int idx = (a < end) ? csr[a] : n;
      uint2 w = *(const uint2*)&Y[(size_t)idx * 16 + 4 * t];
      a01 = hadd2(a01, w.x);
      a23 = hadd2(a23, w.y);
    }
    a01 = hadd2(a01, (unsigned int)__shfl_down((int)a01, 32, 64));
    a23 = hadd2(a23, (unsigned int)__shfl_down((int)a23, 32, 64));
    a01 = hadd2(a01, (unsigned int)__shfl_down((int)a01, 16, 64));
    a23 = hadd2(a23, (unsigned int)__shfl_down((int)a23, 16, 64));
    a01 = hadd2(a01, (unsigned int)__shfl_down((int)a01, 8, 64));
    a23 = hadd2(a23, (unsigned int)__shfl_down((int)a23, 8, 64));
    a01 = hadd2(a01, (unsigned int)__shfl_down((int)a01, 4, 64));
    a23 = hadd2(a23, (unsigned int)__shfl_down((int)a23, 4, 64));
    if (sub == 0) {
      uint2 sv = *(const uint2*)&Y[(size_t)wid * 16 + 4 * t];
      float2 s01 = h22f2(sv.x), s23 = h22f2(sv.y);
      float2 p01 = h22f2(a01), p23 = h22f2(a23);
      float4 bb = *(const float4*)&b2[4 * t];
      float v0f = p01.x + s01.x + bb.x;
      float v1f = p01.y + s01.y + bb.y;
      float v2f = p23.x + s23.x + bb.z;
      float v3f = p23.y + s23.y + bb.w;
      float m = fmaxf(fmaxf(v0f, v1f), fmaxf(v2f, v3f));
      m = fmaxf(m, __shfl_xor(m, 1, 4));
      m = fmaxf(m, __shfl_xor(m, 2, 4));
      float s = expf(v0f - m) + expf(v1f - m) + expf(v2f - m) + expf(v3f - m);
      s += __shfl_xor(s, 1, 4);
      s += __shfl_xor(s, 2, 4);
      float ls = m + logf(s);
      *(float4*)&out[(size_t)wid * 16 + 4 * t] =
          make_float4(v0f - ls, v1f - ls, v2f - ls, v3f - ls);
    }
  }
}

// ---------------------------------------------------------------- launch
extern "C" void kernel_launch(void* const* d_in, const int* in_sizes, int n_in,
                              void* d_out, int out_size, void* d_ws, size_t ws_size,
                              hipStream_t stream) {
  const float* x   = (const float*)d_in[0];
  const int* esrc  = (const int*)d_in[1];
  const int* edst  = (const int*)d_in[2];
  const float* W1  = (const float*)d_in[3];
  // d_in[4] = b1: cancels exactly under batchnorm mean subtraction
  const float* bnw = (const float*)d_in[5];
  const float* bnb = (const float*)d_in[6];
  const float* W2  = (const float*)d_in[7];
  const float* b2  = (const float*)d_in[8];
  float* out = (float*)d_out;

  const int N = in_sizes[0] / 128;  // 100000
  const int E = in_sizes[1];        // 1600000
  const int NB = (N + BNODES - 1) >> BSHIFT;  // 196 buckets

  char* p = (char*)d_ws;
  auto alloc = [&](size_t bytes) {
    char* q = p;
    p += (bytes + 255) & ~(size_t)255;
    return q;
  };
  int* cursor  = (int*)alloc(256 * sizeof(int));
  int* binned  = (int*)alloc((size_t)NB * CAP * sizeof(int));
  int* offs    = (int*)alloc((size_t)(N + 4) * sizeof(int));
  int* csr     = (int*)alloc((size_t)E * sizeof(int));
  float* stats = (float*)alloc((size_t)NSLOT * 128 * sizeof(float));
  unsigned short* Wfrag  = (unsigned short*)alloc(1024 * 8 * sizeof(unsigned short));
  unsigned short* W2frag = (unsigned short*)alloc(128 * 8 * sizeof(unsigned short));
  unsigned short* h1 = (unsigned short*)alloc((size_t)(N + 1) * 64 * sizeof(unsigned short));
  unsigned short* h2 = (unsigned short*)alloc((size_t)(N + 1) * 64 * sizeof(unsigned short));
  unsigned short* h3 = (unsigned short*)alloc((size_t)N * 64 * sizeof(unsigned short));
  unsigned short* Yb = (unsigned short*)alloc((size_t)(N + 1) * 16 * sizeof(unsigned short));

  // setup: zero cursor/stats/pad rows + W1/W2 fragment prep (one dispatch)
  k_setup<<<32, 256, 0, stream>>>(cursor, stats, h1 + (size_t)N * 64,
                                  h2 + (size_t)N * 64, Yb + (size_t)N * 16,
                                  W1, Wfrag, W2, W2frag);

  // fused: edge binning + GEMM1 (independent work, co-resident blocks)
  const int nbin = (E + CHUNK - 1) / CHUNK;
  const int ng1 = (N + 63) / 64;
  k_bin_gemm1<<<nbin + ng1, 256, 0, stream>>>(esrc, edst, cursor, binned, E, nbin,
                                              x, Wfrag, h1, N);
  k_build<<<NB, 512, 0, stream>>>(binned, cursor, offs, csr, N, NB, E);

  // persistent hops at max occupancy (2048 blocks = 8/CU = 32 waves/CU)
  const int nwaves = HOPBLKS * 4;
  k_hop64b<<<HOPBLKS, 256, 0, stream>>>(h1, h2, offs, csr, N, nwaves);
  k_hop64b_stats<<<HOPBLKS, 256, 0, stream>>>(h2, h3, offs, csr, stats, N, nwaves);

  // GEMM2 (MFMA, folded stats-finalize + BN + SELU) then final hop at D=16
  k_gemm2<<<(N + 63) / 64, 256, 0, stream>>>(h3, stats, bnw, bnb, W2frag, Yb, N);
  k_hop16<<<HOPBLKS, 256, 0, stream>>>(Yb, b2, out, offs, csr, N, nwaves);
}